// Round 9
// baseline (585.225 us; speedup 1.0000x reference)
//
#include <hip/hip_runtime.h>
#include <stdint.h>

#define NN 50000
#define NE 800000

// canonical bf16 weight-block element offsets
#define O_WIN 0
#define O_BIN 2048
#define O_WL  2176
#define O_BL  67712
#define O_WR  68224
#define O_LNG 133760
#define O_LNB 134272
#define O_W1  134784
#define O_B1  168576
#define O_W2  168704
#define O_B2  176896
#define O_W3  176960
#define O_B3  177024
#define W_TOTAL 177025

// ws layout (bytes)
#define WS_FLAGS 0          //      256 B
#define WS_WC    512        //  354,050 B
#define WS_CNT   355072     //  200,000 B
#define WS_ROWP  555520     //  200,004 B
#define WS_CUR   756224     //  200,000 B
#define WS_CSR   956928     // 3,200,000 B (src per CSR slot)
#define WS_ED    4156928    // 6,400,000 B (int2 {eid,dst} per CSR slot)
#define WS_W1P   10556928   //     73,728 B
#define WS_HB0   10630656   // 12,800,000 B
#define WS_HB1   23430656   // 12,800,000 B (layer ping-pong; eab after layers)
#define WS_NEED  36230656

#define SCAN_NB 196  // ceil(NN/256)

#define HSTR 304
#define ASTR 560

typedef float f32x4 __attribute__((ext_vector_type(4)));
typedef short bf16x8 __attribute__((ext_vector_type(8)));

__device__ __forceinline__ float b2f(unsigned short u) {
  union { unsigned int i; float f; } v; v.i = ((unsigned int)u) << 16; return v.f;
}
__device__ __forceinline__ float asf(unsigned int u) {
  union { unsigned int i; float f; } v; v.i = u; return v.f;
}
__device__ __forceinline__ unsigned short f2b(float f) {
  union { float f; unsigned int i; } v; v.f = f;
  return (unsigned short)((v.i + 0x7fffu + ((v.i >> 16) & 1u)) >> 16);
}

// raw barrier: LDS-visibility only, does NOT drain vmcnt — keeps the
// next-tile global prefetch loads in flight across the barrier (T14).
#define LBAR() do { \
  asm volatile("s_waitcnt lgkmcnt(0)" ::: "memory"); \
  __builtin_amdgcn_s_barrier(); \
} while (0)

// ---------------- fallback diagnostic: ws too small → constant 0.5 ----------
__global__ void k_fallback(unsigned short* __restrict__ out) {
  int gid = blockIdx.x * 256 + threadIdx.x;
  if (gid < NE) out[gid] = 0x3F00;
}

// ---------------- dtype probe: flags[0]=fp32 float tensors, flags[1]=int64 --
__global__ void k_probe(const unsigned short* __restrict__ x_u,
                        const int* __restrict__ ei32, int* __restrict__ flags) {
  const int t = threadIdx.x;  // 64 threads, 1 wave
  int insane = 0;
  for (int i = t; i < 512; i += 64) {
    float v = b2f(x_u[i]);
    if (!(fabsf(v) < 1e4f)) insane++;
  }
#pragma unroll
  for (int off = 1; off < 64; off <<= 1) insane += __shfl_xor(insane, off, 64);
  int nz = 0;
  for (int i = t; i < 128; i += 64) nz |= (ei32[2 * i + 1] != 0);
  unsigned long long m = __ballot(nz != 0);
  if (t == 0) {
    flags[0] = (insane >= 16) ? 1 : 0;
    flags[1] = (m == 0ULL) ? 1 : 0;
  }
}

// ---------------- canonicalize the 13 weight tensors to bf16 ----------------
__global__ void k_cvt_w(const void* W_in, const void* b_in, const void* Wl,
                        const void* bl, const void* Wr, const void* lng,
                        const void* lnb, const void* W1, const void* b1,
                        const void* W2, const void* b2, const void* W3,
                        const void* b3, unsigned short* __restrict__ wc,
                        const int* __restrict__ flags) {
  const int gid = blockIdx.x * 256 + threadIdx.x;
  if (gid >= W_TOTAL) return;
  const int f32 = flags[0];
  const void* src; int off;
  if      (gid < O_BIN) { src = W_in; off = gid - O_WIN; }
  else if (gid < O_WL)  { src = b_in; off = gid - O_BIN; }
  else if (gid < O_BL)  { src = Wl;   off = gid - O_WL;  }
  else if (gid < O_WR)  { src = bl;   off = gid - O_BL;  }
  else if (gid < O_LNG) { src = Wr;   off = gid - O_WR;  }
  else if (gid < O_LNB) { src = lng;  off = gid - O_LNG; }
  else if (gid < O_W1)  { src = lnb;  off = gid - O_LNB; }
  else if (gid < O_B1)  { src = W1;   off = gid - O_W1;  }
  else if (gid < O_W2)  { src = b1;   off = gid - O_B1;  }
  else if (gid < O_B2)  { src = W2;   off = gid - O_W2;  }
  else if (gid < O_W3)  { src = b2;   off = gid - O_B2;  }
  else if (gid < O_B3)  { src = W3;   off = gid - O_W3;  }
  else                  { src = b3;   off = 0;           }
  wc[gid] = f32 ? f2b(((const float*)src)[off]) : ((const unsigned short*)src)[off];
}

// ---------------- W1 padded copy: wc[128][264] -> W1p[128][288] -------------
__global__ void k_build_w1p(const unsigned short* __restrict__ wc,
                            unsigned short* __restrict__ W1p) {
  int gid = blockIdx.x * 256 + threadIdx.x;  // 128*288 = 36864
  if (gid >= 128 * 288) return;
  int j = gid / 288, k = gid - j * 288;
  W1p[gid] = (k < 264) ? wc[O_W1 + j * 264 + k] : (unsigned short)0;
}

// ---------------- ea → bf16, original edge order (sequential, coalesced) ----
__global__ void k_cvt_ea(const void* __restrict__ ea,
                         unsigned short* __restrict__ eab,
                         const int* __restrict__ flags) {
  const int gid = blockIdx.x * 256 + threadIdx.x;  // NE threads, 8 elems each
  if (gid >= NE) return;
  if (flags[0]) {
    const float4* ep = (const float4*)((const float*)ea + (size_t)gid * 8);
    const float4 a = ep[0], b = ep[1];
    union { ushort4 v[2]; int4 i; } o;
    o.v[0].x = f2b(a.x); o.v[0].y = f2b(a.y); o.v[0].z = f2b(a.z); o.v[0].w = f2b(a.w);
    o.v[1].x = f2b(b.x); o.v[1].y = f2b(b.y); o.v[1].z = f2b(b.z); o.v[1].w = f2b(b.w);
    *(int4*)(eab + (size_t)gid * 8) = o.i;
  } else {
    *(int4*)(eab + (size_t)gid * 8) =
        *(const int4*)((const unsigned short*)ea + (size_t)gid * 8);
  }
}

// ---------------- CSR build: histogram -> 3-phase scan -> fill --------------
__global__ void k_hist(const int* __restrict__ ei, int* __restrict__ cnt,
                       const int* __restrict__ flags) {
  const int e = blockIdx.x * 256 + threadIdx.x;
  if (e >= NE) return;
  const int d = flags[1] ? ei[2 * (NE + e)] : ei[NE + e];
  atomicAdd(&cnt[d], 1);
}

__global__ __launch_bounds__(256) void k_scan1(const int* __restrict__ cnt,
                                               int* __restrict__ rowptr,
                                               int* __restrict__ bsum) {
  __shared__ int ws4[4];
  const int t = threadIdx.x, ln = t & 63, wv = t >> 6;
  const int i = blockIdx.x * 256 + t;
  const int v = (i < NN) ? cnt[i] : 0;
  int x = v;
#pragma unroll
  for (int off = 1; off < 64; off <<= 1) {
    int y = __shfl_up(x, off, 64);
    if (ln >= off) x += y;
  }
  if (ln == 63) ws4[wv] = x;
  __syncthreads();
  if (t == 0) { ws4[1] += ws4[0]; ws4[2] += ws4[1]; ws4[3] += ws4[2]; }
  __syncthreads();
  const int woff = wv ? ws4[wv - 1] : 0;
  if (i < NN) rowptr[i] = woff + x - v;
  if (t == 255) bsum[blockIdx.x] = woff + x;
}

__global__ __launch_bounds__(256) void k_scan2(int* __restrict__ bsum) {
  __shared__ int ws4[4];
  const int t = threadIdx.x, ln = t & 63, wv = t >> 6;
  const int v = (t < SCAN_NB) ? bsum[t] : 0;
  int x = v;
#pragma unroll
  for (int off = 1; off < 64; off <<= 1) {
    int y = __shfl_up(x, off, 64);
    if (ln >= off) x += y;
  }
  if (ln == 63) ws4[wv] = x;
  __syncthreads();
  if (t == 0) { ws4[1] += ws4[0]; ws4[2] += ws4[1]; ws4[3] += ws4[2]; }
  __syncthreads();
  const int woff = wv ? ws4[wv - 1] : 0;
  if (t < SCAN_NB) bsum[t] = woff + x - v;
}

__global__ void k_scan3(int* __restrict__ rowptr, const int* __restrict__ bsum) {
  const int i = blockIdx.x * 256 + threadIdx.x;
  if (i < NN) rowptr[i] += bsum[blockIdx.x];
  if (i == 0) rowptr[NN] = NE;
}

// fill: ONE int2 {eid,dst} write + csr write per edge (2 write-allocated
// lines/edge vs 3 with separate eid/dst arrays — k_fill showed 106MB WRITE).
__global__ void k_fill(const int* __restrict__ ei, const int* __restrict__ rowptr,
                       int* __restrict__ cursor, int* __restrict__ csr,
                       int2* __restrict__ ed, const int* __restrict__ flags) {
  const int e = blockIdx.x * 256 + threadIdx.x;
  if (e >= NE) return;
  const int i64 = flags[1];
  const int s = i64 ? ei[2 * e] : ei[e];
  const int d = i64 ? ei[2 * (NE + e)] : ei[NE + e];
  const int pos = rowptr[d] + atomicAdd(&cursor[d], 1);
  csr[pos] = s;
  ed[pos] = make_int2(e, d);
}

// ---------------- input projection: hb0 = bf16(x @ W_in^T + b_in) -----------
__global__ void k_inproj(const void* __restrict__ x,
                         const unsigned short* __restrict__ wc,
                         unsigned short* __restrict__ hb,
                         const int* __restrict__ flags) {
  const int gid = blockIdx.x * 256 + threadIdx.x;  // NN*128 threads
  const int n = gid >> 7, j = gid & 127;
  float xv[16];
  if (flags[0]) {
    const float4* xp = (const float4*)((const float*)x + (size_t)n * 16);
#pragma unroll
    for (int q = 0; q < 4; q++) {
      float4 t = xp[q];
      xv[q * 4 + 0] = t.x; xv[q * 4 + 1] = t.y; xv[q * 4 + 2] = t.z; xv[q * 4 + 3] = t.w;
    }
  } else {
    const unsigned short* xu = (const unsigned short*)x + (size_t)n * 16;
#pragma unroll
    for (int q = 0; q < 2; q++) {
      union { int4 v; unsigned short u[8]; } t;
      t.v = *(const int4*)(xu + q * 8);
#pragma unroll
      for (int i = 0; i < 8; i++) xv[q * 8 + i] = b2f(t.u[i]);
    }
  }
  float s = b2f(wc[O_BIN + j]);
  const unsigned short* wrow = wc + O_WIN + j * 16;
#pragma unroll
  for (int q = 0; q < 2; q++) {
    union { int4 v; unsigned short u[8]; } w;
    w.v = *(const int4*)(wrow + q * 8);
#pragma unroll
    for (int i = 0; i < 8; i++) s += b2f(w.u[i]) * xv[q * 8 + i];
  }
  hb[gid] = f2b(s);
}

// ---------------- aggregation: mean of neighbor rows, one wave per node -----
__global__ __launch_bounds__(256) void k_agg(
    const unsigned short* __restrict__ hin, const int* __restrict__ csr,
    const int* __restrict__ rowptr, unsigned short* __restrict__ aggb) {
  const int tid = threadIdx.x;
  const int n = blockIdx.x * 4 + (tid >> 6);  // 12500 blocks * 4 waves
  const int L = tid & 63;
  const int rg = L >> 4;   // row-group 0..3 within a 4-row batch
  const int j  = L & 15;   // 16B-column index within a row
  const int rs = rowptr[n], re = rowptr[n + 1];
  const int4* hv = (const int4*)hin;  // one row = 16 int4
  float s[8];
#pragma unroll
  for (int i = 0; i < 8; i++) s[i] = 0.f;

  int e = rs;
  for (; e + 16 <= re; e += 16) {
    int idx[4];
#pragma unroll
    for (int k = 0; k < 4; k++) idx[k] = csr[e + k * 4 + rg];
    int4 u[4];
#pragma unroll
    for (int k = 0; k < 4; k++) u[k] = hv[(size_t)idx[k] * 16 + j];
#pragma unroll
    for (int k = 0; k < 4; k++) {
      const unsigned int w0 = (unsigned int)u[k].x, w1 = (unsigned int)u[k].y;
      const unsigned int w2 = (unsigned int)u[k].z, w3 = (unsigned int)u[k].w;
      s[0] += asf(w0 << 16); s[1] += asf(w0 & 0xffff0000u);
      s[2] += asf(w1 << 16); s[3] += asf(w1 & 0xffff0000u);
      s[4] += asf(w2 << 16); s[5] += asf(w2 & 0xffff0000u);
      s[6] += asf(w3 << 16); s[7] += asf(w3 & 0xffff0000u);
    }
  }
  if (e < re) {
    int idx[4], ok[4];
#pragma unroll
    for (int k = 0; k < 4; k++) {
      const int ee = e + k * 4 + rg;
      ok[k] = ee < re;
      idx[k] = csr[ok[k] ? ee : (re - 1)];
    }
    int4 u[4];
#pragma unroll
    for (int k = 0; k < 4; k++) u[k] = hv[(size_t)idx[k] * 16 + j];
#pragma unroll
    for (int k = 0; k < 4; k++) {
      if (ok[k]) {
        const unsigned int w0 = (unsigned int)u[k].x, w1 = (unsigned int)u[k].y;
        const unsigned int w2 = (unsigned int)u[k].z, w3 = (unsigned int)u[k].w;
        s[0] += asf(w0 << 16); s[1] += asf(w0 & 0xffff0000u);
        s[2] += asf(w1 << 16); s[3] += asf(w1 & 0xffff0000u);
        s[4] += asf(w2 << 16); s[5] += asf(w2 & 0xffff0000u);
        s[6] += asf(w3 << 16); s[7] += asf(w3 & 0xffff0000u);
      }
    }
  }

#pragma unroll
  for (int i = 0; i < 8; i++) {
    s[i] += __shfl_xor(s[i], 16, 64);
    s[i] += __shfl_xor(s[i], 32, 64);
  }
  if (rg == 0) {
    const int dg = re - rs;
    const float rd = 1.0f / (float)(dg > 1 ? dg : 1);
    union { int4 v; unsigned short h[8]; } o;
#pragma unroll
    for (int i = 0; i < 8; i++) o.h[i] = f2b(s[i] * rd);
    ((int4*)aggb)[(size_t)n * 16 + j] = o.v;
  }
}

// ---------------- SAGE layer: MFMA GEMM [agg|h] @ [Wl|Wr]^T + LN + ReLU -----
__global__ __launch_bounds__(256) void k_sage_mfma(
    const unsigned short* __restrict__ hin, unsigned short* __restrict__ hagg,
    const unsigned short* __restrict__ wc, int l) {
  __shared__ __align__(16) unsigned char As[64 * ASTR];  // 35840 B
  __shared__ float red1[64][4];
  __shared__ float red2[64][4];
  __shared__ float mr[64][2];
  const int tid = threadIdx.x;
  const int wv = tid >> 6;
  const int L = tid & 63;
  const int l15 = L & 15;
  const int q = L >> 4;
  const int n0 = blockIdx.x * 64;

  bf16x8 wf[2][8];
  float blv[2], gv[2], bv[2];
#pragma unroll
  for (int nt = 0; nt < 2; nt++) {
    const int jj = (wv * 2 + nt) * 16 + l15;
#pragma unroll
    for (int kc = 0; kc < 8; kc++) {
      const unsigned short* src = (kc < 4)
          ? wc + O_WL + ((size_t)l * 128 + jj) * 128 + kc * 32 + q * 8
          : wc + O_WR + ((size_t)l * 128 + jj) * 128 + (kc - 4) * 32 + q * 8;
      wf[nt][kc] = *(const bf16x8*)src;
    }
    blv[nt] = b2f(wc[O_BL + l * 128 + jj]);
    gv[nt]  = b2f(wc[O_LNG + l * 128 + jj]);
    bv[nt]  = b2f(wc[O_LNB + l * 128 + jj]);
  }

  for (int c = tid; c < 2048; c += 256) {
    const int row = c >> 5, part = c & 31;
    int node = n0 + row; if (node > NN - 1) node = NN - 1;
    const unsigned short* src = (part < 16)
        ? hagg + (size_t)node * 128 + part * 8
        : hin + (size_t)node * 128 + (part - 16) * 8;
    *(int4*)(As + row * ASTR + part * 16) = *(const int4*)src;
  }
  __syncthreads();

  f32x4 acc[4][2];
#pragma unroll
  for (int mt = 0; mt < 4; mt++)
#pragma unroll
    for (int nt = 0; nt < 2; nt++) acc[mt][nt] = (f32x4)(0.0f);
#pragma unroll
  for (int kc = 0; kc < 8; kc++) {
#pragma unroll
    for (int mt = 0; mt < 4; mt++) {
      const bf16x8 a = *(const bf16x8*)(As + (mt * 16 + l15) * ASTR + (kc * 32 + q * 8) * 2);
#pragma unroll
      for (int nt = 0; nt < 2; nt++)
        acc[mt][nt] = __builtin_amdgcn_mfma_f32_16x16x32_bf16(a, wf[nt][kc], acc[mt][nt], 0, 0, 0);
    }
  }
#pragma unroll
  for (int mt = 0; mt < 4; mt++) {
#pragma unroll
    for (int rg = 0; rg < 4; rg++) {
      acc[mt][0][rg] += blv[0];
      acc[mt][1][rg] += blv[1];
      float s = acc[mt][0][rg] + acc[mt][1][rg];
      float s2 = acc[mt][0][rg] * acc[mt][0][rg] + acc[mt][1][rg] * acc[mt][1][rg];
#pragma unroll
      for (int m = 1; m < 16; m <<= 1) {
        s += __shfl_xor(s, m, 64);
        s2 += __shfl_xor(s2, m, 64);
      }
      if (l15 == 0) {
        const int row = mt * 16 + q * 4 + rg;
        red1[row][wv] = s; red2[row][wv] = s2;
      }
    }
  }
  __syncthreads();
  if (tid < 64) {
    const float s1 = red1[tid][0] + red1[tid][1] + red1[tid][2] + red1[tid][3];
    const float s2 = red2[tid][0] + red2[tid][1] + red2[tid][2] + red2[tid][3];
    const float mu = s1 * 0.0078125f;
    const float var = s2 * 0.0078125f - mu * mu;
    mr[tid][0] = mu;
    mr[tid][1] = rsqrtf(var + 1e-5f);
  }
  __syncthreads();
#pragma unroll
  for (int mt = 0; mt < 4; mt++) {
#pragma unroll
    for (int rg = 0; rg < 4; rg++) {
      const int row = mt * 16 + q * 4 + rg;
      const int node = n0 + row;
      if (node < NN) {
        const float mu = mr[row][0], rstd = mr[row][1];
#pragma unroll
        for (int nt = 0; nt < 2; nt++) {
          const float o = (acc[mt][nt][rg] - mu) * rstd * gv[nt] + bv[nt];
          hagg[(size_t)node * 128 + (wv * 2 + nt) * 16 + l15] = f2b(fmaxf(o, 0.f));
        }
      }
    }
  }
}

// ---------------- edge head: 3-barrier pipelined dst-grouped MFMA MLP -------
// GEMM2 restructured: each wave computes its OWN 16 edge-rows x all 64 cols
// (w2f[4][4] in regs), so e2 lives in accumulators; GEMM3 is an in-register
// dot + 16-lane shfl reduce. E2 buffer, its bank conflicts, and one barrier
// are gone (4 -> 3 barriers/tile). No LDS aliasing: Hs/Ds/E1 separate.
// Hazards: Hs/Ds/Ue reads finish >=2 barriers before their next write; E1
// reads drain at each wave's lgkmcnt(0) before LBAR-A, writes after LBAR-B.
// LDS: Ue 4096 | Hs 19456 | Ds 19456 | E1 19456 = 62464 B.
__global__ __launch_bounds__(256) void k_edge_mfma(
    const unsigned short* __restrict__ hb, const int* __restrict__ csr,
    const int2* __restrict__ ed, const unsigned short* __restrict__ eab,
    const unsigned short* __restrict__ W1p, const unsigned short* __restrict__ wc,
    void* __restrict__ out, const int* __restrict__ flags) {
  __shared__ __align__(16) unsigned char sm[62464];
  unsigned char* const Ue = sm;            // [64][64B]    0..4096
  unsigned char* const Hs = sm + 4096;     // [64][304B]   4096..23552
  unsigned char* const Ds = sm + 23552;    // [64][304B]   23552..43008
  unsigned char* const E1 = sm + 43008;    // [64][304B]   43008..62464
  const int tid = threadIdx.x;
  const int wv = tid >> 6;
  const int L = tid & 63;
  const int l15 = L & 15;
  const int q = L >> 4;
  const int f32 = flags[0];
  const int r4 = tid >> 2, seg = tid & 3;

  // zero the K-padding region of Ue (bytes 16..63 of each 64B row), once.
  for (int i = tid; i < 64 * 12; i += 256)
    *(int*)(Ue + (i / 12) * 64 + 16 + (i % 12) * 4) = 0;

  bf16x8 w1f[2][9];
  float b1v[2];
#pragma unroll
  for (int nt = 0; nt < 2; nt++) {
    const int jj = (wv * 2 + nt) * 16 + l15;
#pragma unroll
    for (int cc = 0; cc < 9; cc++)
      w1f[nt][cc] = *(const bf16x8*)(W1p + jj * 288 + cc * 32 + q * 8);
    b1v[nt] = b2f(wc[O_B1 + jj]);
  }
  // GEMM2 weights: all 64 output cols per wave (col = nt*16 + l15)
  bf16x8 w2f[4][4];
  float b2v[4], w3v[4];
#pragma unroll
  for (int nt = 0; nt < 4; nt++) {
    const int jj = nt * 16 + l15;
#pragma unroll
    for (int kc = 0; kc < 4; kc++)
      w2f[nt][kc] = *(const bf16x8*)(wc + O_W2 + jj * 128 + kc * 32 + q * 8);
    b2v[nt] = b2f(wc[O_B2 + jj]);
    w3v[nt] = b2f(wc[O_W3 + jj]);
  }
  const float b3f = b2f(wc[O_B3]);

  const int NT = NE / 64;

  // -------- prologue: prefetch first tile into registers --------
  int4 hsr0, hsr1, hsr2, hsr3;     // src row fragment
  int4 dsr0, dsr1, dsr2, dsr3;     // dst row fragment
  int4 uer; uer.x = uer.y = uer.z = uer.w = 0;
  {
    const int p0 = blockIdx.x * 64;
    const int s0 = csr[p0 + r4];
    const int d0 = ed[p0 + r4].y;
    const unsigned short* gs = hb + (size_t)s0 * 128 + seg * 32;
    const unsigned short* gd = hb + (size_t)d0 * 128 + seg * 32;
    hsr0 = ((const int4*)gs)[0]; hsr1 = ((const int4*)gs)[1];
    hsr2 = ((const int4*)gs)[2]; hsr3 = ((const int4*)gs)[3];
    dsr0 = ((const int4*)gd)[0]; dsr1 = ((const int4*)gd)[1];
    dsr2 = ((const int4*)gd)[2]; dsr3 = ((const int4*)gd)[3];
    if (tid < 64) {
      const int e0 = ed[p0 + tid].x;
      uer = *(const int4*)(eab + (size_t)e0 * 8);
    }
  }

  for (int t = blockIdx.x; t < NT; t += gridDim.x) {
    const int pbase = t * 64;
    const int tn = (t + (int)gridDim.x < NT) ? (t + (int)gridDim.x) : t;
    const int pnext = tn * 64;

    // 1. LDS writes from current-tile registers (vmcnt waits auto-inserted).
    //    Safe without a preceding barrier: all Hs/Ds/Ue reads completed
    //    before the previous iteration's post-GEMM1 barrier.
    if (tid < 64) *(int4*)(Ue + tid * 64) = uer;
    {
      unsigned char* ldst = Hs + r4 * HSTR + seg * 64;
      ((int4*)ldst)[0] = hsr0; ((int4*)ldst)[1] = hsr1;
      ((int4*)ldst)[2] = hsr2; ((int4*)ldst)[3] = hsr3;
      unsigned char* ldd = Ds + r4 * HSTR + seg * 64;
      ((int4*)ldd)[0] = dsr0; ((int4*)ldd)[1] = dsr1;
      ((int4*)ldd)[2] = dsr2; ((int4*)ldd)[3] = dsr3;
    }
    // 2. next-tile index loads (sequential, L2-hot)
    const int sN = csr[pnext + r4];
    const int dN = ed[pnext + r4].y;
    int eN = 0;
    if (tid < 64) eN = ed[pnext + tid].x;

    LBAR();  // A: Hs/Ds/Ue visible (also fences prior GEMM2's E1 reads)

    // 3. next-tile row gathers — stay in flight across GEMM1/2/3
    int4 h0, h1, h2, h3, d0, d1, d2, d3;
    {
      const unsigned short* gsn = hb + (size_t)sN * 128 + seg * 32;
      h0 = ((const int4*)gsn)[0]; h1 = ((const int4*)gsn)[1];
      h2 = ((const int4*)gsn)[2]; h3 = ((const int4*)gsn)[3];
      const unsigned short* gdn = hb + (size_t)dN * 128 + seg * 32;
      d0 = ((const int4*)gdn)[0]; d1 = ((const int4*)gdn)[1];
      d2 = ((const int4*)gdn)[2]; d3 = ((const int4*)gdn)[3];
    }
    int4 uen; uen.x = uen.y = uen.z = uen.w = 0;
    if (tid < 64) uen = *(const int4*)(eab + (size_t)eN * 8);

    // 4. GEMM1: e1[64][128]; src (Hs), dst (Ds), ea (Ue) — all from LDS
    f32x4 acc1[4][2];
#pragma unroll
    for (int mt = 0; mt < 4; mt++)
#pragma unroll
      for (int nt = 0; nt < 2; nt++) acc1[mt][nt] = (f32x4)(0.0f);
#pragma unroll
    for (int cc = 0; cc < 4; cc++) {
#pragma unroll
      for (int mt = 0; mt < 4; mt++) {
        const bf16x8 a = *(const bf16x8*)(Hs + (mt * 16 + l15) * HSTR + (cc * 32 + q * 8) * 2);
#pragma unroll
        for (int nt = 0; nt < 2; nt++)
          acc1[mt][nt] = __builtin_amdgcn_mfma_f32_16x16x32_bf16(a, w1f[nt][cc], acc1[mt][nt], 0, 0, 0);
      }
    }
#pragma unroll
    for (int cc = 4; cc < 8; cc++) {
#pragma unroll
      for (int mt = 0; mt < 4; mt++) {
        const bf16x8 a = *(const bf16x8*)(Ds + (mt * 16 + l15) * HSTR + ((cc - 4) * 32 + q * 8) * 2);
#pragma unroll
        for (int nt = 0; nt < 2; nt++)
          acc1[mt][nt] = __builtin_amdgcn_mfma_f32_16x16x32_bf16(a, w1f[nt][cc], acc1[mt][nt], 0, 0, 0);
      }
    }
#pragma unroll
    for (int mt = 0; mt < 4; mt++) {
      const bf16x8 a = *(const bf16x8*)(Ue + (mt * 16 + l15) * 64 + q * 16);
#pragma unroll
      for (int nt = 0; nt < 2; nt++)
        acc1[mt][nt] = __builtin_amdgcn_mfma_f32_16x16x32_bf16(a, w1f[nt][8], acc1[mt][nt], 0, 0, 0);
    }
    LBAR();  // B: all waves past GEMM1 -> E1 writes may begin

#pragma unroll
    for (int mt = 0; mt < 4; mt++)
#pragma unroll
      for (int nt = 0; nt < 2; nt++)
#pragma unroll
        for (int rg = 0; rg < 4; rg++) {
          const int er = mt * 16 + q * 4 + rg;
          const int jj = (wv * 2 + nt) * 16 + l15;
          *(unsigned short*)(E1 + er * HSTR + jj * 2) =
              f2b(fmaxf(acc1[mt][nt][rg] + b1v[nt], 0.f));
        }
    LBAR();  // C: E1 visible

    // GEMM2: wave computes its OWN 16 rows x all 64 cols; e2 in registers
    f32x4 acc2[4];
#pragma unroll
    for (int nt = 0; nt < 4; nt++) acc2[nt] = (f32x4)(0.0f);
#pragma unroll
    for (int kc = 0; kc < 4; kc++) {
      const bf16x8 a = *(const bf16x8*)(E1 + (wv * 16 + l15) * HSTR + (kc * 32 + q * 8) * 2);
#pragma unroll
      for (int nt = 0; nt < 4; nt++)
        acc2[nt] = __builtin_amdgcn_mfma_f32_16x16x32_bf16(a, w2f[nt][kc], acc2[nt], 0, 0, 0);
    }

    // GEMM3 in-register: lane (q,l15) holds e2[wv*16+q*4+rg][nt*16+l15];
    // logit[r] = sum over cols -> per-lane dot then 16-lane shfl reduce.
    float p[4];
#pragma unroll
    for (int rg = 0; rg < 4; rg++) {
      float s = 0.f;
#pragma unroll
      for (int nt = 0; nt < 4; nt++)
        s += fmaxf(acc2[nt][rg] + b2v[nt], 0.f) * w3v[nt];
      p[rg] = s;
    }
#pragma unroll
    for (int off = 1; off < 16; off <<= 1)
#pragma unroll
      for (int rg = 0; rg < 4; rg++) p[rg] += __shfl_xor(p[rg], off, 64);
    if (l15 == 0) {
#pragma unroll
      for (int rg = 0; rg < 4; rg++) {
        const int slot = pbase + wv * 16 + q * 4 + rg;
        const int e = ed[slot].x;
        const float r = p[rg] + b3f;
        if (f32) ((float*)out)[e] = r;
        else     ((unsigned short*)out)[e] = f2b(r);
      }
    }

    // rotate prefetch registers
    hsr0 = h0; hsr1 = h1; hsr2 = h2; hsr3 = h3;
    dsr0 = d0; dsr1 = d1; dsr2 = d2; dsr3 = d3;
    uer = uen;
  }
}

extern "C" void kernel_launch(void* const* d_in, const int* in_sizes, int n_in,
                              void* d_out, int out_size, void* d_ws, size_t ws_size,
                              hipStream_t stream) {
  const void* x  = d_in[0];
  const int*  ei = (const int*)d_in[1];
  const void* ea = d_in[2];

  char* ws = (char*)d_ws;
  int*            flags  = (int*)(ws + WS_FLAGS);
  unsigned short* wc     = (unsigned short*)(ws + WS_WC);
  int*            cnt    = (int*)(ws + WS_CNT);
  int*            rowptr = (int*)(ws + WS_ROWP);
  int*            cursor = (int*)(ws + WS_CUR);
  int*            csr    = (int*)(ws + WS_CSR);
  int2*           ed     = (int2*)(ws + WS_ED);
  unsigned short* W1p    = (unsigned short*)(ws + WS_W1P);
  unsigned short* hb0    = (unsigned short*)(ws + WS_HB0);
  unsigned short* hb1    = (unsigned short*)(ws + WS_HB1);
  // bsum lives in the CSR slot: used only between k_scan1 and k_scan3,
  // k_fill overwrites csr afterwards.
  int*            bsum   = (int*)(ws + WS_CSR);

  if (ws_size < WS_NEED) {  // diagnostic: error ≈ 1.35 signals this path
    k_fallback<<<3125, 256, 0, stream>>>((unsigned short*)d_out);
    return;
  }

  k_probe<<<1, 64, 0, stream>>>((const unsigned short*)x, ei, flags);
  k_cvt_w<<<(W_TOTAL + 255) / 256, 256, 0, stream>>>(
      d_in[3], d_in[4], d_in[5], d_in[6], d_in[7], d_in[8], d_in[9],
      d_in[10], d_in[11], d_in[12], d_in[13], d_in[14], d_in[15], wc, flags);
  k_build_w1p<<<144, 256, 0, stream>>>(wc, W1p);

  hipMemsetAsync(cnt, 0, NN * sizeof(int), stream);
  hipMemsetAsync(cursor, 0, NN * sizeof(int), stream);
  k_hist<<<3125, 256, 0, stream>>>(ei, cnt, flags);
  k_scan1<<<SCAN_NB, 256, 0, stream>>>(cnt, rowptr, bsum);
  k_scan2<<<1, 256, 0, stream>>>(bsum);
  k_scan3<<<SCAN_NB, 256, 0, stream>>>(rowptr, bsum);
  k_fill<<<3125, 256, 0, stream>>>(ei, rowptr, cursor, csr, ed, flags);

  k_inproj<<<NN * 128 / 256, 256, 0, stream>>>(x, wc, hb0, flags);

  unsigned short* cur = hb0;
  unsigned short* nxt = hb1;
  for (int l = 0; l < 4; l++) {
    k_agg<<<12500, 256, 0, stream>>>(cur, csr, rowptr, nxt);
    k_sage_mfma<<<782, 256, 0, stream>>>(cur, nxt, wc, l);
    unsigned short* tmp = cur; cur = nxt; nxt = tmp;
  }
  // after 4 swaps, final h is in hb0 (= cur); hb1 (= nxt) is free → reuse as eab
  unsigned short* eab = nxt;
  k_cvt_ea<<<3125, 256, 0, stream>>>(ea, eab, flags);
  k_edge_mfma<<<3125, 256, 0, stream>>>(cur, csr, ed, eab, W1p, wc, d_out, flags);
}

// Round 10
// 576.250 us; speedup vs baseline: 1.0156x; 1.0156x over previous
//
#include <hip/hip_runtime.h>
#include <stdint.h>

#define NN 50000
#define NE 800000

// canonical bf16 weight-block element offsets
#define O_WIN 0
#define O_BIN 2048
#define O_WL  2176
#define O_BL  67712
#define O_WR  68224
#define O_LNG 133760
#define O_LNB 134272
#define O_W1  134784
#define O_B1  168576
#define O_W2  168704
#define O_B2  176896
#define O_W3  176960
#define O_B3  177024
#define W_TOTAL 177025

// ws layout (bytes)
#define WS_FLAGS 0          //      256 B
#define WS_WC    512        //  354,050 B
#define WS_CNT   355072     //  200,000 B
#define WS_ROWP  555520     //  200,004 B
#define WS_CUR   756224     //  200,000 B
#define WS_CSR   956928     // 3,200,000 B (src per CSR slot)
#define WS_ED    4156928    // 6,400,000 B (int2 {eid,dst} per CSR slot)
#define WS_W1P   10556928   //     73,728 B
#define WS_HB0   10630656   // 12,800,000 B
#define WS_HB1   23430656   // 12,800,000 B (layer ping-pong; eab after layers)
#define WS_NEED  36230656

#define SCAN_NB 196  // ceil(NN/256)

#define HSTR 336   // Hs/E1 row stride: [src 256 | ea 16 | zero pad 64]
#define DSTR 304   // Ds row stride
#define ASTR 560

typedef float f32x4 __attribute__((ext_vector_type(4)));
typedef short bf16x8 __attribute__((ext_vector_type(8)));
typedef short bf16x4 __attribute__((ext_vector_type(4)));

__device__ __forceinline__ float b2f(unsigned short u) {
  union { unsigned int i; float f; } v; v.i = ((unsigned int)u) << 16; return v.f;
}
__device__ __forceinline__ float asf(unsigned int u) {
  union { unsigned int i; float f; } v; v.i = u; return v.f;
}
__device__ __forceinline__ unsigned short f2b(float f) {
  union { float f; unsigned int i; } v; v.f = f;
  return (unsigned short)((v.i + 0x7fffu + ((v.i >> 16) & 1u)) >> 16);
}

// raw barrier: LDS-visibility only, does NOT drain vmcnt — keeps the
// next-tile global prefetch loads in flight across the barrier (T14).
#define LBAR() do { \
  asm volatile("s_waitcnt lgkmcnt(0)" ::: "memory"); \
  __builtin_amdgcn_s_barrier(); \
} while (0)

// ---------------- fallback diagnostic: ws too small → constant 0.5 ----------
__global__ void k_fallback(unsigned short* __restrict__ out) {
  int gid = blockIdx.x * 256 + threadIdx.x;
  if (gid < NE) out[gid] = 0x3F00;
}

// ---------------- dtype probe: flags[0]=fp32 float tensors, flags[1]=int64 --
__global__ void k_probe(const unsigned short* __restrict__ x_u,
                        const int* __restrict__ ei32, int* __restrict__ flags) {
  const int t = threadIdx.x;  // 64 threads, 1 wave
  int insane = 0;
  for (int i = t; i < 512; i += 64) {
    float v = b2f(x_u[i]);
    if (!(fabsf(v) < 1e4f)) insane++;
  }
#pragma unroll
  for (int off = 1; off < 64; off <<= 1) insane += __shfl_xor(insane, off, 64);
  int nz = 0;
  for (int i = t; i < 128; i += 64) nz |= (ei32[2 * i + 1] != 0);
  unsigned long long m = __ballot(nz != 0);
  if (t == 0) {
    flags[0] = (insane >= 16) ? 1 : 0;
    flags[1] = (m == 0ULL) ? 1 : 0;
  }
}

// ---------------- canonicalize the 13 weight tensors to bf16 ----------------
__global__ void k_cvt_w(const void* W_in, const void* b_in, const void* Wl,
                        const void* bl, const void* Wr, const void* lng,
                        const void* lnb, const void* W1, const void* b1,
                        const void* W2, const void* b2, const void* W3,
                        const void* b3, unsigned short* __restrict__ wc,
                        const int* __restrict__ flags) {
  const int gid = blockIdx.x * 256 + threadIdx.x;
  if (gid >= W_TOTAL) return;
  const int f32 = flags[0];
  const void* src; int off;
  if      (gid < O_BIN) { src = W_in; off = gid - O_WIN; }
  else if (gid < O_WL)  { src = b_in; off = gid - O_BIN; }
  else if (gid < O_BL)  { src = Wl;   off = gid - O_WL;  }
  else if (gid < O_WR)  { src = bl;   off = gid - O_BL;  }
  else if (gid < O_LNG) { src = Wr;   off = gid - O_WR;  }
  else if (gid < O_LNB) { src = lng;  off = gid - O_LNG; }
  else if (gid < O_W1)  { src = lnb;  off = gid - O_LNB; }
  else if (gid < O_B1)  { src = W1;   off = gid - O_W1;  }
  else if (gid < O_W2)  { src = b1;   off = gid - O_B1;  }
  else if (gid < O_B2)  { src = W2;   off = gid - O_W2;  }
  else if (gid < O_W3)  { src = b2;   off = gid - O_B2;  }
  else if (gid < O_B3)  { src = W3;   off = gid - O_W3;  }
  else                  { src = b3;   off = 0;           }
  wc[gid] = f32 ? f2b(((const float*)src)[off]) : ((const unsigned short*)src)[off];
}

// ---------------- W1 padded copy: wc[128][264] -> W1p[128][288] -------------
__global__ void k_build_w1p(const unsigned short* __restrict__ wc,
                            unsigned short* __restrict__ W1p) {
  int gid = blockIdx.x * 256 + threadIdx.x;  // 128*288 = 36864
  if (gid >= 128 * 288) return;
  int j = gid / 288, k = gid - j * 288;
  W1p[gid] = (k < 264) ? wc[O_W1 + j * 264 + k] : (unsigned short)0;
}

// ---------------- ea → bf16, original edge order (sequential, coalesced) ----
__global__ void k_cvt_ea(const void* __restrict__ ea,
                         unsigned short* __restrict__ eab,
                         const int* __restrict__ flags) {
  const int gid = blockIdx.x * 256 + threadIdx.x;  // NE threads, 8 elems each
  if (gid >= NE) return;
  if (flags[0]) {
    const float4* ep = (const float4*)((const float*)ea + (size_t)gid * 8);
    const float4 a = ep[0], b = ep[1];
    union { ushort4 v[2]; int4 i; } o;
    o.v[0].x = f2b(a.x); o.v[0].y = f2b(a.y); o.v[0].z = f2b(a.z); o.v[0].w = f2b(a.w);
    o.v[1].x = f2b(b.x); o.v[1].y = f2b(b.y); o.v[1].z = f2b(b.z); o.v[1].w = f2b(b.w);
    *(int4*)(eab + (size_t)gid * 8) = o.i;
  } else {
    *(int4*)(eab + (size_t)gid * 8) =
        *(const int4*)((const unsigned short*)ea + (size_t)gid * 8);
  }
}

// ---------------- CSR build: histogram -> 3-phase scan -> fill --------------
__global__ void k_hist(const int* __restrict__ ei, int* __restrict__ cnt,
                       const int* __restrict__ flags) {
  const int e = blockIdx.x * 256 + threadIdx.x;
  if (e >= NE) return;
  const int d = flags[1] ? ei[2 * (NE + e)] : ei[NE + e];
  atomicAdd(&cnt[d], 1);
}

__global__ __launch_bounds__(256) void k_scan1(const int* __restrict__ cnt,
                                               int* __restrict__ rowptr,
                                               int* __restrict__ bsum) {
  __shared__ int ws4[4];
  const int t = threadIdx.x, ln = t & 63, wv = t >> 6;
  const int i = blockIdx.x * 256 + t;
  const int v = (i < NN) ? cnt[i] : 0;
  int x = v;
#pragma unroll
  for (int off = 1; off < 64; off <<= 1) {
    int y = __shfl_up(x, off, 64);
    if (ln >= off) x += y;
  }
  if (ln == 63) ws4[wv] = x;
  __syncthreads();
  if (t == 0) { ws4[1] += ws4[0]; ws4[2] += ws4[1]; ws4[3] += ws4[2]; }
  __syncthreads();
  const int woff = wv ? ws4[wv - 1] : 0;
  if (i < NN) rowptr[i] = woff + x - v;
  if (t == 255) bsum[blockIdx.x] = woff + x;
}

__global__ __launch_bounds__(256) void k_scan2(int* __restrict__ bsum) {
  __shared__ int ws4[4];
  const int t = threadIdx.x, ln = t & 63, wv = t >> 6;
  const int v = (t < SCAN_NB) ? bsum[t] : 0;
  int x = v;
#pragma unroll
  for (int off = 1; off < 64; off <<= 1) {
    int y = __shfl_up(x, off, 64);
    if (ln >= off) x += y;
  }
  if (ln == 63) ws4[wv] = x;
  __syncthreads();
  if (t == 0) { ws4[1] += ws4[0]; ws4[2] += ws4[1]; ws4[3] += ws4[2]; }
  __syncthreads();
  const int woff = wv ? ws4[wv - 1] : 0;
  if (t < SCAN_NB) bsum[t] = woff + x - v;
}

__global__ void k_scan3(int* __restrict__ rowptr, const int* __restrict__ bsum) {
  const int i = blockIdx.x * 256 + threadIdx.x;
  if (i < NN) rowptr[i] += bsum[blockIdx.x];
  if (i == 0) rowptr[NN] = NE;
}

// fill: ONE int2 {eid,dst} write + csr write per edge (2 write-allocated
// lines/edge vs 3 with separate eid/dst arrays).
__global__ void k_fill(const int* __restrict__ ei, const int* __restrict__ rowptr,
                       int* __restrict__ cursor, int* __restrict__ csr,
                       int2* __restrict__ ed, const int* __restrict__ flags) {
  const int e = blockIdx.x * 256 + threadIdx.x;
  if (e >= NE) return;
  const int i64 = flags[1];
  const int s = i64 ? ei[2 * e] : ei[e];
  const int d = i64 ? ei[2 * (NE + e)] : ei[NE + e];
  const int pos = rowptr[d] + atomicAdd(&cursor[d], 1);
  csr[pos] = s;
  ed[pos] = make_int2(e, d);
}

// ---------------- input projection: hb0 = bf16(x @ W_in^T + b_in) -----------
__global__ void k_inproj(const void* __restrict__ x,
                         const unsigned short* __restrict__ wc,
                         unsigned short* __restrict__ hb,
                         const int* __restrict__ flags) {
  const int gid = blockIdx.x * 256 + threadIdx.x;  // NN*128 threads
  const int n = gid >> 7, j = gid & 127;
  float xv[16];
  if (flags[0]) {
    const float4* xp = (const float4*)((const float*)x + (size_t)n * 16);
#pragma unroll
    for (int q = 0; q < 4; q++) {
      float4 t = xp[q];
      xv[q * 4 + 0] = t.x; xv[q * 4 + 1] = t.y; xv[q * 4 + 2] = t.z; xv[q * 4 + 3] = t.w;
    }
  } else {
    const unsigned short* xu = (const unsigned short*)x + (size_t)n * 16;
#pragma unroll
    for (int q = 0; q < 2; q++) {
      union { int4 v; unsigned short u[8]; } t;
      t.v = *(const int4*)(xu + q * 8);
#pragma unroll
      for (int i = 0; i < 8; i++) xv[q * 8 + i] = b2f(t.u[i]);
    }
  }
  float s = b2f(wc[O_BIN + j]);
  const unsigned short* wrow = wc + O_WIN + j * 16;
#pragma unroll
  for (int q = 0; q < 2; q++) {
    union { int4 v; unsigned short u[8]; } w;
    w.v = *(const int4*)(wrow + q * 8);
#pragma unroll
    for (int i = 0; i < 8; i++) s += b2f(w.u[i]) * xv[q * 8 + i];
  }
  hb[gid] = f2b(s);
}

// ---------------- aggregation: mean of neighbor rows, one wave per node -----
__global__ __launch_bounds__(256) void k_agg(
    const unsigned short* __restrict__ hin, const int* __restrict__ csr,
    const int* __restrict__ rowptr, unsigned short* __restrict__ aggb) {
  const int tid = threadIdx.x;
  const int n = blockIdx.x * 4 + (tid >> 6);  // 12500 blocks * 4 waves
  const int L = tid & 63;
  const int rg = L >> 4;   // row-group 0..3 within a 4-row batch
  const int j  = L & 15;   // 16B-column index within a row
  const int rs = rowptr[n], re = rowptr[n + 1];
  const int4* hv = (const int4*)hin;  // one row = 16 int4
  float s[8];
#pragma unroll
  for (int i = 0; i < 8; i++) s[i] = 0.f;

  int e = rs;
  for (; e + 16 <= re; e += 16) {
    int idx[4];
#pragma unroll
    for (int k = 0; k < 4; k++) idx[k] = csr[e + k * 4 + rg];
    int4 u[4];
#pragma unroll
    for (int k = 0; k < 4; k++) u[k] = hv[(size_t)idx[k] * 16 + j];
#pragma unroll
    for (int k = 0; k < 4; k++) {
      const unsigned int w0 = (unsigned int)u[k].x, w1 = (unsigned int)u[k].y;
      const unsigned int w2 = (unsigned int)u[k].z, w3 = (unsigned int)u[k].w;
      s[0] += asf(w0 << 16); s[1] += asf(w0 & 0xffff0000u);
      s[2] += asf(w1 << 16); s[3] += asf(w1 & 0xffff0000u);
      s[4] += asf(w2 << 16); s[5] += asf(w2 & 0xffff0000u);
      s[6] += asf(w3 << 16); s[7] += asf(w3 & 0xffff0000u);
    }
  }
  if (e < re) {
    int idx[4], ok[4];
#pragma unroll
    for (int k = 0; k < 4; k++) {
      const int ee = e + k * 4 + rg;
      ok[k] = ee < re;
      idx[k] = csr[ok[k] ? ee : (re - 1)];
    }
    int4 u[4];
#pragma unroll
    for (int k = 0; k < 4; k++) u[k] = hv[(size_t)idx[k] * 16 + j];
#pragma unroll
    for (int k = 0; k < 4; k++) {
      if (ok[k]) {
        const unsigned int w0 = (unsigned int)u[k].x, w1 = (unsigned int)u[k].y;
        const unsigned int w2 = (unsigned int)u[k].z, w3 = (unsigned int)u[k].w;
        s[0] += asf(w0 << 16); s[1] += asf(w0 & 0xffff0000u);
        s[2] += asf(w1 << 16); s[3] += asf(w1 & 0xffff0000u);
        s[4] += asf(w2 << 16); s[5] += asf(w2 & 0xffff0000u);
        s[6] += asf(w3 << 16); s[7] += asf(w3 & 0xffff0000u);
      }
    }
  }

#pragma unroll
  for (int i = 0; i < 8; i++) {
    s[i] += __shfl_xor(s[i], 16, 64);
    s[i] += __shfl_xor(s[i], 32, 64);
  }
  if (rg == 0) {
    const int dg = re - rs;
    const float rd = 1.0f / (float)(dg > 1 ? dg : 1);
    union { int4 v; unsigned short h[8]; } o;
#pragma unroll
    for (int i = 0; i < 8; i++) o.h[i] = f2b(s[i] * rd);
    ((int4*)aggb)[(size_t)n * 16 + j] = o.v;
  }
}

// ---------------- SAGE layer: MFMA GEMM [agg|h] @ [Wl|Wr]^T + LN + ReLU -----
__global__ __launch_bounds__(256) void k_sage_mfma(
    const unsigned short* __restrict__ hin, unsigned short* __restrict__ hagg,
    const unsigned short* __restrict__ wc, int l) {
  __shared__ __align__(16) unsigned char As[64 * ASTR];  // 35840 B
  __shared__ float red1[64][4];
  __shared__ float red2[64][4];
  __shared__ float mr[64][2];
  const int tid = threadIdx.x;
  const int wv = tid >> 6;
  const int L = tid & 63;
  const int l15 = L & 15;
  const int q = L >> 4;
  const int n0 = blockIdx.x * 64;

  bf16x8 wf[2][8];
  float blv[2], gv[2], bv[2];
#pragma unroll
  for (int nt = 0; nt < 2; nt++) {
    const int jj = (wv * 2 + nt) * 16 + l15;
#pragma unroll
    for (int kc = 0; kc < 8; kc++) {
      const unsigned short* src = (kc < 4)
          ? wc + O_WL + ((size_t)l * 128 + jj) * 128 + kc * 32 + q * 8
          : wc + O_WR + ((size_t)l * 128 + jj) * 128 + (kc - 4) * 32 + q * 8;
      wf[nt][kc] = *(const bf16x8*)src;
    }
    blv[nt] = b2f(wc[O_BL + l * 128 + jj]);
    gv[nt]  = b2f(wc[O_LNG + l * 128 + jj]);
    bv[nt]  = b2f(wc[O_LNB + l * 128 + jj]);
  }

  for (int c = tid; c < 2048; c += 256) {
    const int row = c >> 5, part = c & 31;
    int node = n0 + row; if (node > NN - 1) node = NN - 1;
    const unsigned short* src = (part < 16)
        ? hagg + (size_t)node * 128 + part * 8
        : hin + (size_t)node * 128 + (part - 16) * 8;
    *(int4*)(As + row * ASTR + part * 16) = *(const int4*)src;
  }
  __syncthreads();

  f32x4 acc[4][2];
#pragma unroll
  for (int mt = 0; mt < 4; mt++)
#pragma unroll
    for (int nt = 0; nt < 2; nt++) acc[mt][nt] = (f32x4)(0.0f);
#pragma unroll
  for (int kc = 0; kc < 8; kc++) {
#pragma unroll
    for (int mt = 0; mt < 4; mt++) {
      const bf16x8 a = *(const bf16x8*)(As + (mt * 16 + l15) * ASTR + (kc * 32 + q * 8) * 2);
#pragma unroll
      for (int nt = 0; nt < 2; nt++)
        acc[mt][nt] = __builtin_amdgcn_mfma_f32_16x16x32_bf16(a, wf[nt][kc], acc[mt][nt], 0, 0, 0);
    }
  }
#pragma unroll
  for (int mt = 0; mt < 4; mt++) {
#pragma unroll
    for (int rg = 0; rg < 4; rg++) {
      acc[mt][0][rg] += blv[0];
      acc[mt][1][rg] += blv[1];
      float s = acc[mt][0][rg] + acc[mt][1][rg];
      float s2 = acc[mt][0][rg] * acc[mt][0][rg] + acc[mt][1][rg] * acc[mt][1][rg];
#pragma unroll
      for (int m = 1; m < 16; m <<= 1) {
        s += __shfl_xor(s, m, 64);
        s2 += __shfl_xor(s2, m, 64);
      }
      if (l15 == 0) {
        const int row = mt * 16 + q * 4 + rg;
        red1[row][wv] = s; red2[row][wv] = s2;
      }
    }
  }
  __syncthreads();
  if (tid < 64) {
    const float s1 = red1[tid][0] + red1[tid][1] + red1[tid][2] + red1[tid][3];
    const float s2 = red2[tid][0] + red2[tid][1] + red2[tid][2] + red2[tid][3];
    const float mu = s1 * 0.0078125f;
    const float var = s2 * 0.0078125f - mu * mu;
    mr[tid][0] = mu;
    mr[tid][1] = rsqrtf(var + 1e-5f);
  }
  __syncthreads();
#pragma unroll
  for (int mt = 0; mt < 4; mt++) {
#pragma unroll
    for (int rg = 0; rg < 4; rg++) {
      const int row = mt * 16 + q * 4 + rg;
      const int node = n0 + row;
      if (node < NN) {
        const float mu = mr[row][0], rstd = mr[row][1];
#pragma unroll
        for (int nt = 0; nt < 2; nt++) {
          const float o = (acc[mt][nt][rg] - mu) * rstd * gv[nt] + bv[nt];
          hagg[(size_t)node * 128 + (wv * 2 + nt) * 16 + l15] = f2b(fmaxf(o, 0.f));
        }
      }
    }
  }
}

// ---------------- edge head: T14 pipelined dst-grouped MFMA MLP -------------
// Round-8 proven structure (4 barriers, E2 buffer, original GEMM2) with two
// bank-conflict fixes that do NOT touch GEMM structure:
//  (a) ea merged into Hs rows: [src 256 | ea 16 | zero pad 64], stride 336
//      -> no Ue buffer, no 32-way 64B-stride staging pileup; ea MFMA reads
//      Hs+256+q*16 (q>0 hits the once-zeroed pad = K-padding).
//  (b) E1 write packed b32 via W1 column permutation (jj = wv*32+2*l15+nt):
//      lane's two nt-outputs are adjacent columns -> 16 b32 writes at 2-way
//      (free) instead of 32 scalar b16. E1 CONTENT layout unchanged; GEMM2
//      reads untouched (rounds 5+9 proved GEMM2 restructures regress).
// LDS: Hs/E1 21504 (aliased) | Ds 19456 | E2 8704 = 49664 B.
__global__ __launch_bounds__(256) void k_edge_mfma(
    const unsigned short* __restrict__ hb, const int* __restrict__ csr,
    const int2* __restrict__ ed, const unsigned short* __restrict__ eab,
    const unsigned short* __restrict__ W1p, const unsigned short* __restrict__ wc,
    void* __restrict__ out, const int* __restrict__ flags) {
  __shared__ __align__(16) unsigned char sm[49664];
  unsigned char* const Hs = sm;            // [64][336B]   0..21504
  unsigned char* const E1 = sm;            // aliases Hs bytes 0..255/row
  unsigned char* const Ds = sm + 21504;    // [64][304B]   21504..40960
  unsigned char* const E2 = sm + 40960;    // [64][136B]   40960..49664
  const int tid = threadIdx.x;
  const int wv = tid >> 6;
  const int L = tid & 63;
  const int l15 = L & 15;
  const int q = L >> 4;
  const int f32 = flags[0];
  const int r4 = tid >> 2, seg = tid & 3;

  // zero the K-padding bytes 272..335 of each Hs row, once (never rewritten:
  // staging touches 0..271, E1 aliases 0..255).
  for (int i = tid; i < 1024; i += 256)
    *(int*)(Hs + (i >> 4) * HSTR + 272 + (i & 15) * 4) = 0;

  // GEMM1 weights, permuted columns: frag nt, lane l15 -> physical col
  // wv*32 + 2*l15 + nt (adjacent pairs per lane -> packed E1 writes).
  bf16x8 w1f[2][9];
  float b1v[2];
#pragma unroll
  for (int nt = 0; nt < 2; nt++) {
    const int jj = wv * 32 + l15 * 2 + nt;
#pragma unroll
    for (int cc = 0; cc < 9; cc++)
      w1f[nt][cc] = *(const bf16x8*)(W1p + jj * 288 + cc * 32 + q * 8);
    b1v[nt] = b2f(wc[O_B1 + jj]);
  }
  bf16x8 w2f[4];
  const int jj2 = wv * 16 + l15;
#pragma unroll
  for (int kc = 0; kc < 4; kc++)
    w2f[kc] = *(const bf16x8*)(wc + O_W2 + jj2 * 128 + kc * 32 + q * 8);
  const float b2v = b2f(wc[O_B2 + jj2]);
  const float b3f = b2f(wc[O_B3]);

  const int NT = NE / 64;

  // -------- prologue: prefetch first tile into registers --------
  int4 hsr0, hsr1, hsr2, hsr3;     // src row fragment
  int4 dsr0, dsr1, dsr2, dsr3;     // dst row fragment
  int4 uer; uer.x = uer.y = uer.z = uer.w = 0;
  {
    const int p0 = blockIdx.x * 64;
    const int s0 = csr[p0 + r4];
    const int d0 = ed[p0 + r4].y;
    const unsigned short* gs = hb + (size_t)s0 * 128 + seg * 32;
    const unsigned short* gd = hb + (size_t)d0 * 128 + seg * 32;
    hsr0 = ((const int4*)gs)[0]; hsr1 = ((const int4*)gs)[1];
    hsr2 = ((const int4*)gs)[2]; hsr3 = ((const int4*)gs)[3];
    dsr0 = ((const int4*)gd)[0]; dsr1 = ((const int4*)gd)[1];
    dsr2 = ((const int4*)gd)[2]; dsr3 = ((const int4*)gd)[3];
    if (tid < 64) {
      const int e0 = ed[p0 + tid].x;
      uer = *(const int4*)(eab + (size_t)e0 * 8);
    }
  }

  for (int t = blockIdx.x; t < NT; t += gridDim.x) {
    const int pbase = t * 64;
    const int tn = (t + (int)gridDim.x < NT) ? (t + (int)gridDim.x) : t;
    const int pnext = tn * 64;

    // 1. LDS writes from current-tile registers (vmcnt waits auto-inserted)
    if (tid < 64) *(int4*)(Hs + tid * HSTR + 256) = uer;  // ea slot
    {
      unsigned char* ldst = Hs + r4 * HSTR + seg * 64;
      ((int4*)ldst)[0] = hsr0; ((int4*)ldst)[1] = hsr1;
      ((int4*)ldst)[2] = hsr2; ((int4*)ldst)[3] = hsr3;
      unsigned char* ldd = Ds + r4 * DSTR + seg * 64;
      ((int4*)ldd)[0] = dsr0; ((int4*)ldd)[1] = dsr1;
      ((int4*)ldd)[2] = dsr2; ((int4*)ldd)[3] = dsr3;
    }
    // 2. next-tile index loads (sequential, L2-hot)
    const int sN = csr[pnext + r4];
    const int dN = ed[pnext + r4].y;
    int eN = 0;
    if (tid < 64) eN = ed[pnext + tid].x;

    LBAR();  // A: Hs/Ds/ea visible

    // 3. next-tile row gathers — stay in flight across GEMM1/2/3
    int4 h0, h1, h2, h3, d0, d1, d2, d3;
    {
      const unsigned short* gsn = hb + (size_t)sN * 128 + seg * 32;
      h0 = ((const int4*)gsn)[0]; h1 = ((const int4*)gsn)[1];
      h2 = ((const int4*)gsn)[2]; h3 = ((const int4*)gsn)[3];
      const unsigned short* gdn = hb + (size_t)dN * 128 + seg * 32;
      d0 = ((const int4*)gdn)[0]; d1 = ((const int4*)gdn)[1];
      d2 = ((const int4*)gdn)[2]; d3 = ((const int4*)gdn)[3];
    }
    int4 uen; uen.x = uen.y = uen.z = uen.w = 0;
    if (tid < 64) uen = *(const int4*)(eab + (size_t)eN * 8);

    // 4. GEMM1: e1[64][128]; src (Hs), dst (Ds), ea (Hs+256) — all from LDS
    f32x4 acc1[4][2];
#pragma unroll
    for (int mt = 0; mt < 4; mt++)
#pragma unroll
      for (int nt = 0; nt < 2; nt++) acc1[mt][nt] = (f32x4)(0.0f);
#pragma unroll
    for (int cc = 0; cc < 4; cc++) {
#pragma unroll
      for (int mt = 0; mt < 4; mt++) {
        const bf16x8 a = *(const bf16x8*)(Hs + (mt * 16 + l15) * HSTR + (cc * 32 + q * 8) * 2);
#pragma unroll
        for (int nt = 0; nt < 2; nt++)
          acc1[mt][nt] = __builtin_amdgcn_mfma_f32_16x16x32_bf16(a, w1f[nt][cc], acc1[mt][nt], 0, 0, 0);
      }
    }
#pragma unroll
    for (int cc = 4; cc < 8; cc++) {
#pragma unroll
      for (int mt = 0; mt < 4; mt++) {
        const bf16x8 a = *(const bf16x8*)(Ds + (mt * 16 + l15) * DSTR + ((cc - 4) * 32 + q * 8) * 2);
#pragma unroll
        for (int nt = 0; nt < 2; nt++)
          acc1[mt][nt] = __builtin_amdgcn_mfma_f32_16x16x32_bf16(a, w1f[nt][cc], acc1[mt][nt], 0, 0, 0);
      }
    }
#pragma unroll
    for (int mt = 0; mt < 4; mt++) {
      const bf16x8 a = *(const bf16x8*)(Hs + (mt * 16 + l15) * HSTR + 256 + q * 16);
#pragma unroll
      for (int nt = 0; nt < 2; nt++)
        acc1[mt][nt] = __builtin_amdgcn_mfma_f32_16x16x32_bf16(a, w1f[nt][8], acc1[mt][nt], 0, 0, 0);
    }
    LBAR();  // B: all waves done reading Hs/Ds/ea -> E1 may overwrite Hs

    // E1 epilogue: packed b32 writes (adjacent-column pairs per lane, 2-way)
#pragma unroll
    for (int mt = 0; mt < 4; mt++)
#pragma unroll
      for (int rg = 0; rg < 4; rg++) {
        const int er = mt * 16 + q * 4 + rg;
        const float v0 = fmaxf(acc1[mt][0][rg] + b1v[0], 0.f);
        const float v1 = fmaxf(acc1[mt][1][rg] + b1v[1], 0.f);
        const unsigned int pk =
            (unsigned int)f2b(v0) | ((unsigned int)f2b(v1) << 16);
        *(unsigned int*)(E1 + er * HSTR + (wv * 32 + l15 * 2) * 2) = pk;
      }
    LBAR();  // C: E1 visible

    // GEMM2: e2[64][64], wave covers 16 cols, all 64 rows (proven form)
    f32x4 acc2[4];
#pragma unroll
    for (int mt = 0; mt < 4; mt++) acc2[mt] = (f32x4)(0.0f);
#pragma unroll
    for (int kc = 0; kc < 4; kc++) {
#pragma unroll
      for (int mt = 0; mt < 4; mt++) {
        const bf16x8 a = *(const bf16x8*)(E1 + (mt * 16 + l15) * HSTR + (kc * 32 + q * 8) * 2);
        acc2[mt] = __builtin_amdgcn_mfma_f32_16x16x32_bf16(a, w2f[kc], acc2[mt], 0, 0, 0);
      }
    }
#pragma unroll
    for (int mt = 0; mt < 4; mt++)
#pragma unroll
      for (int rg = 0; rg < 4; rg++) {
        const int er = mt * 16 + q * 4 + rg;
        *(unsigned short*)(E2 + er * 136 + jj2 * 2) =
            f2b(fmaxf(acc2[mt][rg] + b2v, 0.f));
      }
    LBAR();  // D: E2 visible

    // GEMM3: logit per edge, dot-64 via 4 lane-groups + shuffle; scatter by eid
    const int el = wv * 16 + l15;
    float acc = 0.f;
#pragma unroll
    for (int i4 = 0; i4 < 4; i4++) {
      const bf16x4 v = *(const bf16x4*)(E2 + el * 136 + q * 32 + i4 * 8);
#pragma unroll
      for (int j = 0; j < 4; j++)
        acc += b2f((unsigned short)v[j]) * b2f(wc[O_W3 + q * 16 + i4 * 4 + j]);
    }
    acc += __shfl_xor(acc, 16, 64);
    acc += __shfl_xor(acc, 32, 64);
    if (q == 0) {
      const int e = ed[pbase + el].x;
      const float r = acc + b3f;
      if (f32) ((float*)out)[e] = r;
      else     ((unsigned short*)out)[e] = f2b(r);
    }

    // rotate prefetch registers
    hsr0 = h0; hsr1 = h1; hsr2 = h2; hsr3 = h3;
    dsr0 = d0; dsr1 = d1; dsr2 = d2; dsr3 = d3;
    uer = uen;
  }
}

extern "C" void kernel_launch(void* const* d_in, const int* in_sizes, int n_in,
                              void* d_out, int out_size, void* d_ws, size_t ws_size,
                              hipStream_t stream) {
  const void* x  = d_in[0];
  const int*  ei = (const int*)d_in[1];
  const void* ea = d_in[2];

  char* ws = (char*)d_ws;
  int*            flags  = (int*)(ws + WS_FLAGS);
  unsigned short* wc     = (unsigned short*)(ws + WS_WC);
  int*            cnt    = (int*)(ws + WS_CNT);
  int*            rowptr = (int*)(ws + WS_ROWP);
  int*            cursor = (int*)(ws + WS_CUR);
  int*            csr    = (int*)(ws + WS_CSR);
  int2*           ed     = (int2*)(ws + WS_ED);
  unsigned short* W1p    = (unsigned short*)(ws + WS_W1P);
  unsigned short* hb0    = (unsigned short*)(ws + WS_HB0);
  unsigned short* hb1    = (unsigned short*)(ws + WS_HB1);
  // bsum lives in the CSR slot: used only between k_scan1 and k_scan3,
  // k_fill overwrites csr afterwards.
  int*            bsum   = (int*)(ws + WS_CSR);

  if (ws_size < WS_NEED) {  // diagnostic: error ≈ 1.35 signals this path
    k_fallback<<<3125, 256, 0, stream>>>((unsigned short*)d_out);
    return;
  }

  k_probe<<<1, 64, 0, stream>>>((const unsigned short*)x, ei, flags);
  k_cvt_w<<<(W_TOTAL + 255) / 256, 256, 0, stream>>>(
      d_in[3], d_in[4], d_in[5], d_in[6], d_in[7], d_in[8], d_in[9],
      d_in[10], d_in[11], d_in[12], d_in[13], d_in[14], d_in[15], wc, flags);
  k_build_w1p<<<144, 256, 0, stream>>>(wc, W1p);

  hipMemsetAsync(cnt, 0, NN * sizeof(int), stream);
  hipMemsetAsync(cursor, 0, NN * sizeof(int), stream);
  k_hist<<<3125, 256, 0, stream>>>(ei, cnt, flags);
  k_scan1<<<SCAN_NB, 256, 0, stream>>>(cnt, rowptr, bsum);
  k_scan2<<<1, 256, 0, stream>>>(bsum);
  k_scan3<<<SCAN_NB, 256, 0, stream>>>(rowptr, bsum);
  k_fill<<<3125, 256, 0, stream>>>(ei, rowptr, cursor, csr, ed, flags);

  k_inproj<<<NN * 128 / 256, 256, 0, stream>>>(x, wc, hb0, flags);

  unsigned short* cur = hb0;
  unsigned short* nxt = hb1;
  for (int l = 0; l < 4; l++) {
    k_agg<<<12500, 256, 0, stream>>>(cur, csr, rowptr, nxt);
    k_sage_mfma<<<782, 256, 0, stream>>>(cur, nxt, wc, l);
    unsigned short* tmp = cur; cur = nxt; nxt = tmp;
  }
  // after 4 swaps, final h is in hb0 (= cur); hb1 (= nxt) is free → reuse as eab
  unsigned short* eab = nxt;
  k_cvt_ea<<<3125, 256, 0, stream>>>(ea, eab, flags);
  k_edge_mfma<<<3125, 256, 0, stream>>>(cur, csr, ed, eab, W1p, wc, d_out, flags);
}

// Round 11
// 556.472 us; speedup vs baseline: 1.0517x; 1.0355x over previous
//
#include <hip/hip_runtime.h>
#include <stdint.h>

#define NN 50000
#define NE 800000

// canonical bf16 weight-block element offsets
#define O_WIN 0
#define O_BIN 2048
#define O_WL  2176
#define O_BL  67712
#define O_WR  68224
#define O_LNG 133760
#define O_LNB 134272
#define O_W1  134784
#define O_B1  168576
#define O_W2  168704
#define O_B2  176896
#define O_W3  176960
#define O_B3  177024
#define W_TOTAL 177025

// ws layout (bytes)
#define WS_FLAGS 0          //      256 B
#define WS_WC    512        //  354,050 B
#define WS_CNT   355072     //  200,000 B
#define WS_ROWP  555520     //  200,004 B
#define WS_CUR   756224     //  200,000 B
#define WS_CSR   956928     // 3,200,000 B (src per CSR slot)
#define WS_EID   4156928    // 3,200,000 B (edge id per CSR slot)
#define WS_DST   7356928    // 3,200,000 B (dst per CSR slot)
#define WS_W1P   10556928   //     73,728 B
#define WS_HB0   10630656   // 12,800,000 B
#define WS_HB1   23430656   // 12,800,000 B (layer ping-pong; eab after layers)
#define WS_NEED  36230656

#define SCAN_NB 196  // ceil(NN/256)

#define HSTR 304
#define ASTR 560

typedef float f32x4 __attribute__((ext_vector_type(4)));
typedef short bf16x8 __attribute__((ext_vector_type(8)));
typedef short bf16x4 __attribute__((ext_vector_type(4)));

__device__ __forceinline__ float b2f(unsigned short u) {
  union { unsigned int i; float f; } v; v.i = ((unsigned int)u) << 16; return v.f;
}
__device__ __forceinline__ float asf(unsigned int u) {
  union { unsigned int i; float f; } v; v.i = u; return v.f;
}
__device__ __forceinline__ unsigned short f2b(float f) {
  union { float f; unsigned int i; } v; v.f = f;
  return (unsigned short)((v.i + 0x7fffu + ((v.i >> 16) & 1u)) >> 16);
}

// raw barrier: LDS-visibility only, does NOT drain vmcnt — keeps the
// next-tile global prefetch loads in flight across the barrier (T14).
#define LBAR() do { \
  asm volatile("s_waitcnt lgkmcnt(0)" ::: "memory"); \
  __builtin_amdgcn_s_barrier(); \
} while (0)

// ---------------- fallback diagnostic: ws too small → constant 0.5 ----------
__global__ void k_fallback(unsigned short* __restrict__ out) {
  int gid = blockIdx.x * 256 + threadIdx.x;
  if (gid < NE) out[gid] = 0x3F00;
}

// ---------------- dtype probe: flags[0]=fp32 float tensors, flags[1]=int64 --
__global__ void k_probe(const unsigned short* __restrict__ x_u,
                        const int* __restrict__ ei32, int* __restrict__ flags) {
  const int t = threadIdx.x;  // 64 threads, 1 wave
  int insane = 0;
  for (int i = t; i < 512; i += 64) {
    float v = b2f(x_u[i]);
    if (!(fabsf(v) < 1e4f)) insane++;
  }
#pragma unroll
  for (int off = 1; off < 64; off <<= 1) insane += __shfl_xor(insane, off, 64);
  int nz = 0;
  for (int i = t; i < 128; i += 64) nz |= (ei32[2 * i + 1] != 0);
  unsigned long long m = __ballot(nz != 0);
  if (t == 0) {
    flags[0] = (insane >= 16) ? 1 : 0;
    flags[1] = (m == 0ULL) ? 1 : 0;
  }
}

// ---------------- canonicalize the 13 weight tensors to bf16 ----------------
__global__ void k_cvt_w(const void* W_in, const void* b_in, const void* Wl,
                        const void* bl, const void* Wr, const void* lng,
                        const void* lnb, const void* W1, const void* b1,
                        const void* W2, const void* b2, const void* W3,
                        const void* b3, unsigned short* __restrict__ wc,
                        const int* __restrict__ flags) {
  const int gid = blockIdx.x * 256 + threadIdx.x;
  if (gid >= W_TOTAL) return;
  const int f32 = flags[0];
  const void* src; int off;
  if      (gid < O_BIN) { src = W_in; off = gid - O_WIN; }
  else if (gid < O_WL)  { src = b_in; off = gid - O_BIN; }
  else if (gid < O_BL)  { src = Wl;   off = gid - O_WL;  }
  else if (gid < O_WR)  { src = bl;   off = gid - O_BL;  }
  else if (gid < O_LNG) { src = Wr;   off = gid - O_WR;  }
  else if (gid < O_LNB) { src = lng;  off = gid - O_LNG; }
  else if (gid < O_W1)  { src = lnb;  off = gid - O_LNB; }
  else if (gid < O_B1)  { src = W1;   off = gid - O_W1;  }
  else if (gid < O_W2)  { src = b1;   off = gid - O_B1;  }
  else if (gid < O_B2)  { src = W2;   off = gid - O_W2;  }
  else if (gid < O_W3)  { src = b2;   off = gid - O_B2;  }
  else if (gid < O_B3)  { src = W3;   off = gid - O_W3;  }
  else                  { src = b3;   off = 0;           }
  wc[gid] = f32 ? f2b(((const float*)src)[off]) : ((const unsigned short*)src)[off];
}

// ---------------- W1 padded copy: wc[128][264] -> W1p[128][288] -------------
__global__ void k_build_w1p(const unsigned short* __restrict__ wc,
                            unsigned short* __restrict__ W1p) {
  int gid = blockIdx.x * 256 + threadIdx.x;  // 128*288 = 36864
  if (gid >= 128 * 288) return;
  int j = gid / 288, k = gid - j * 288;
  W1p[gid] = (k < 264) ? wc[O_W1 + j * 264 + k] : (unsigned short)0;
}

// ---------------- ea → bf16, original edge order (sequential, coalesced) ----
__global__ void k_cvt_ea(const void* __restrict__ ea,
                         unsigned short* __restrict__ eab,
                         const int* __restrict__ flags) {
  const int gid = blockIdx.x * 256 + threadIdx.x;  // NE threads, 8 elems each
  if (gid >= NE) return;
  if (flags[0]) {
    const float4* ep = (const float4*)((const float*)ea + (size_t)gid * 8);
    const float4 a = ep[0], b = ep[1];
    union { ushort4 v[2]; int4 i; } o;
    o.v[0].x = f2b(a.x); o.v[0].y = f2b(a.y); o.v[0].z = f2b(a.z); o.v[0].w = f2b(a.w);
    o.v[1].x = f2b(b.x); o.v[1].y = f2b(b.y); o.v[1].z = f2b(b.z); o.v[1].w = f2b(b.w);
    *(int4*)(eab + (size_t)gid * 8) = o.i;
  } else {
    *(int4*)(eab + (size_t)gid * 8) =
        *(const int4*)((const unsigned short*)ea + (size_t)gid * 8);
  }
}

// ---------------- CSR build: histogram -> 3-phase scan -> fill --------------
__global__ void k_hist(const int* __restrict__ ei, int* __restrict__ cnt,
                       const int* __restrict__ flags) {
  const int e = blockIdx.x * 256 + threadIdx.x;
  if (e >= NE) return;
  const int d = flags[1] ? ei[2 * (NE + e)] : ei[NE + e];
  atomicAdd(&cnt[d], 1);
}

// phase 1: per-block exclusive local prefix into rowptr, block sum into bsum
__global__ __launch_bounds__(256) void k_scan1(const int* __restrict__ cnt,
                                               int* __restrict__ rowptr,
                                               int* __restrict__ bsum) {
  __shared__ int ws4[4];
  const int t = threadIdx.x, ln = t & 63, wv = t >> 6;
  const int i = blockIdx.x * 256 + t;
  const int v = (i < NN) ? cnt[i] : 0;
  int x = v;
#pragma unroll
  for (int off = 1; off < 64; off <<= 1) {
    int y = __shfl_up(x, off, 64);
    if (ln >= off) x += y;
  }
  if (ln == 63) ws4[wv] = x;
  __syncthreads();
  if (t == 0) { ws4[1] += ws4[0]; ws4[2] += ws4[1]; ws4[3] += ws4[2]; }
  __syncthreads();
  const int woff = wv ? ws4[wv - 1] : 0;
  if (i < NN) rowptr[i] = woff + x - v;
  if (t == 255) bsum[blockIdx.x] = woff + x;
}

// phase 2: single block, exclusive scan of the 196 block sums in place
__global__ __launch_bounds__(256) void k_scan2(int* __restrict__ bsum) {
  __shared__ int ws4[4];
  const int t = threadIdx.x, ln = t & 63, wv = t >> 6;
  const int v = (t < SCAN_NB) ? bsum[t] : 0;
  int x = v;
#pragma unroll
  for (int off = 1; off < 64; off <<= 1) {
    int y = __shfl_up(x, off, 64);
    if (ln >= off) x += y;
  }
  if (ln == 63) ws4[wv] = x;
  __syncthreads();
  if (t == 0) { ws4[1] += ws4[0]; ws4[2] += ws4[1]; ws4[3] += ws4[2]; }
  __syncthreads();
  const int woff = wv ? ws4[wv - 1] : 0;
  if (t < SCAN_NB) bsum[t] = woff + x - v;
}

// phase 3: add block offsets
__global__ void k_scan3(int* __restrict__ rowptr, const int* __restrict__ bsum) {
  const int i = blockIdx.x * 256 + threadIdx.x;
  if (i < NN) rowptr[i] += bsum[blockIdx.x];
  if (i == 0) rowptr[NN] = NE;
}

__global__ void k_fill(const int* __restrict__ ei, const int* __restrict__ rowptr,
                       int* __restrict__ cursor, int* __restrict__ csr,
                       int* __restrict__ eidA, int* __restrict__ dstA,
                       const int* __restrict__ flags) {
  const int e = blockIdx.x * 256 + threadIdx.x;
  if (e >= NE) return;
  const int i64 = flags[1];
  const int s = i64 ? ei[2 * e] : ei[e];
  const int d = i64 ? ei[2 * (NE + e)] : ei[NE + e];
  const int pos = rowptr[d] + atomicAdd(&cursor[d], 1);
  csr[pos] = s;
  eidA[pos] = e;
  dstA[pos] = d;
}

// ---------------- input projection: hb0 = bf16(x @ W_in^T + b_in) -----------
__global__ void k_inproj(const void* __restrict__ x,
                         const unsigned short* __restrict__ wc,
                         unsigned short* __restrict__ hb,
                         const int* __restrict__ flags) {
  const int gid = blockIdx.x * 256 + threadIdx.x;  // NN*128 threads
  const int n = gid >> 7, j = gid & 127;
  float xv[16];
  if (flags[0]) {
    const float4* xp = (const float4*)((const float*)x + (size_t)n * 16);
#pragma unroll
    for (int q = 0; q < 4; q++) {
      float4 t = xp[q];
      xv[q * 4 + 0] = t.x; xv[q * 4 + 1] = t.y; xv[q * 4 + 2] = t.z; xv[q * 4 + 3] = t.w;
    }
  } else {
    const unsigned short* xu = (const unsigned short*)x + (size_t)n * 16;
#pragma unroll
    for (int q = 0; q < 2; q++) {
      union { int4 v; unsigned short u[8]; } t;
      t.v = *(const int4*)(xu + q * 8);
#pragma unroll
      for (int i = 0; i < 8; i++) xv[q * 8 + i] = b2f(t.u[i]);
    }
  }
  float s = b2f(wc[O_BIN + j]);
  const unsigned short* wrow = wc + O_WIN + j * 16;
#pragma unroll
  for (int q = 0; q < 2; q++) {
    union { int4 v; unsigned short u[8]; } w;
    w.v = *(const int4*)(wrow + q * 8);
#pragma unroll
    for (int i = 0; i < 8; i++) s += b2f(w.u[i]) * xv[q * 8 + i];
  }
  hb[gid] = f2b(s);
}

// ---------------- aggregation: mean of neighbor rows, one wave per node -----
// int4 gather: 16 lanes cover one row (16B each), one load instruction moves
// 4 rows (1KB/wave). f32 accumulation, deterministic: fixed lane partition
// + fixed 2-step shfl_xor(16,32) tree. Measured plateau ~2.85 TB/s random-
// 256B-row gather from the 12.8MB LLC-resident array (k_edge converges to
// the same rate at 4x lower occupancy -> structural, not TLP-limited).
__global__ __launch_bounds__(256) void k_agg(
    const unsigned short* __restrict__ hin, const int* __restrict__ csr,
    const int* __restrict__ rowptr, unsigned short* __restrict__ aggb) {
  const int tid = threadIdx.x;
  const int n = blockIdx.x * 4 + (tid >> 6);  // 12500 blocks * 4 waves
  const int L = tid & 63;
  const int rg = L >> 4;   // row-group 0..3 within a 4-row batch
  const int j  = L & 15;   // 16B-column index within a row
  const int rs = rowptr[n], re = rowptr[n + 1];
  const int4* hv = (const int4*)hin;  // one row = 16 int4
  float s[8];
#pragma unroll
  for (int i = 0; i < 8; i++) s[i] = 0.f;

  int e = rs;
  for (; e + 16 <= re; e += 16) {
    int idx[4];
#pragma unroll
    for (int k = 0; k < 4; k++) idx[k] = csr[e + k * 4 + rg];
    int4 u[4];
#pragma unroll
    for (int k = 0; k < 4; k++) u[k] = hv[(size_t)idx[k] * 16 + j];
#pragma unroll
    for (int k = 0; k < 4; k++) {
      const unsigned int w0 = (unsigned int)u[k].x, w1 = (unsigned int)u[k].y;
      const unsigned int w2 = (unsigned int)u[k].z, w3 = (unsigned int)u[k].w;
      s[0] += asf(w0 << 16); s[1] += asf(w0 & 0xffff0000u);
      s[2] += asf(w1 << 16); s[3] += asf(w1 & 0xffff0000u);
      s[4] += asf(w2 << 16); s[5] += asf(w2 & 0xffff0000u);
      s[6] += asf(w3 << 16); s[7] += asf(w3 & 0xffff0000u);
    }
  }
  if (e < re) {
    int idx[4], ok[4];
#pragma unroll
    for (int k = 0; k < 4; k++) {
      const int ee = e + k * 4 + rg;
      ok[k] = ee < re;
      idx[k] = csr[ok[k] ? ee : (re - 1)];
    }
    int4 u[4];
#pragma unroll
    for (int k = 0; k < 4; k++) u[k] = hv[(size_t)idx[k] * 16 + j];
#pragma unroll
    for (int k = 0; k < 4; k++) {
      if (ok[k]) {
        const unsigned int w0 = (unsigned int)u[k].x, w1 = (unsigned int)u[k].y;
        const unsigned int w2 = (unsigned int)u[k].z, w3 = (unsigned int)u[k].w;
        s[0] += asf(w0 << 16); s[1] += asf(w0 & 0xffff0000u);
        s[2] += asf(w1 << 16); s[3] += asf(w1 & 0xffff0000u);
        s[4] += asf(w2 << 16); s[5] += asf(w2 & 0xffff0000u);
        s[6] += asf(w3 << 16); s[7] += asf(w3 & 0xffff0000u);
      }
    }
  }

#pragma unroll
  for (int i = 0; i < 8; i++) {
    s[i] += __shfl_xor(s[i], 16, 64);
    s[i] += __shfl_xor(s[i], 32, 64);
  }
  if (rg == 0) {
    const int dg = re - rs;
    const float rd = 1.0f / (float)(dg > 1 ? dg : 1);
    union { int4 v; unsigned short h[8]; } o;
#pragma unroll
    for (int i = 0; i < 8; i++) o.h[i] = f2b(s[i] * rd);
    ((int4*)aggb)[(size_t)n * 16 + j] = o.v;
  }
}

// ---------------- SAGE layer: MFMA GEMM [agg|h] @ [Wl|Wr]^T + LN + ReLU -----
__global__ __launch_bounds__(256) void k_sage_mfma(
    const unsigned short* __restrict__ hin, unsigned short* __restrict__ hagg,
    const unsigned short* __restrict__ wc, int l) {
  __shared__ __align__(16) unsigned char As[64 * ASTR];  // 35840 B
  __shared__ float red1[64][4];
  __shared__ float red2[64][4];
  __shared__ float mr[64][2];
  const int tid = threadIdx.x;
  const int wv = tid >> 6;
  const int L = tid & 63;
  const int l15 = L & 15;
  const int q = L >> 4;
  const int n0 = blockIdx.x * 64;

  bf16x8 wf[2][8];
  float blv[2], gv[2], bv[2];
#pragma unroll
  for (int nt = 0; nt < 2; nt++) {
    const int jj = (wv * 2 + nt) * 16 + l15;
#pragma unroll
    for (int kc = 0; kc < 8; kc++) {
      const unsigned short* src = (kc < 4)
          ? wc + O_WL + ((size_t)l * 128 + jj) * 128 + kc * 32 + q * 8
          : wc + O_WR + ((size_t)l * 128 + jj) * 128 + (kc - 4) * 32 + q * 8;
      wf[nt][kc] = *(const bf16x8*)src;
    }
    blv[nt] = b2f(wc[O_BL + l * 128 + jj]);
    gv[nt]  = b2f(wc[O_LNG + l * 128 + jj]);
    bv[nt]  = b2f(wc[O_LNB + l * 128 + jj]);
  }

  for (int c = tid; c < 2048; c += 256) {
    const int row = c >> 5, part = c & 31;
    int node = n0 + row; if (node > NN - 1) node = NN - 1;
    const unsigned short* src = (part < 16)
        ? hagg + (size_t)node * 128 + part * 8
        : hin + (size_t)node * 128 + (part - 16) * 8;
    *(int4*)(As + row * ASTR + part * 16) = *(const int4*)src;
  }
  __syncthreads();

  f32x4 acc[4][2];
#pragma unroll
  for (int mt = 0; mt < 4; mt++)
#pragma unroll
    for (int nt = 0; nt < 2; nt++) acc[mt][nt] = (f32x4)(0.0f);
#pragma unroll
  for (int kc = 0; kc < 8; kc++) {
#pragma unroll
    for (int mt = 0; mt < 4; mt++) {
      const bf16x8 a = *(const bf16x8*)(As + (mt * 16 + l15) * ASTR + (kc * 32 + q * 8) * 2);
#pragma unroll
      for (int nt = 0; nt < 2; nt++)
        acc[mt][nt] = __builtin_amdgcn_mfma_f32_16x16x32_bf16(a, wf[nt][kc], acc[mt][nt], 0, 0, 0);
    }
  }
#pragma unroll
  for (int mt = 0; mt < 4; mt++) {
#pragma unroll
    for (int rg = 0; rg < 4; rg++) {
      acc[mt][0][rg] += blv[0];
      acc[mt][1][rg] += blv[1];
      float s = acc[mt][0][rg] + acc[mt][1][rg];
      float s2 = acc[mt][0][rg] * acc[mt][0][rg] + acc[mt][1][rg] * acc[mt][1][rg];
#pragma unroll
      for (int m = 1; m < 16; m <<= 1) {
        s += __shfl_xor(s, m, 64);
        s2 += __shfl_xor(s2, m, 64);
      }
      if (l15 == 0) {
        const int row = mt * 16 + q * 4 + rg;
        red1[row][wv] = s; red2[row][wv] = s2;
      }
    }
  }
  __syncthreads();
  if (tid < 64) {
    const float s1 = red1[tid][0] + red1[tid][1] + red1[tid][2] + red1[tid][3];
    const float s2 = red2[tid][0] + red2[tid][1] + red2[tid][2] + red2[tid][3];
    const float mu = s1 * 0.0078125f;
    const float var = s2 * 0.0078125f - mu * mu;
    mr[tid][0] = mu;
    mr[tid][1] = rsqrtf(var + 1e-5f);
  }
  __syncthreads();
#pragma unroll
  for (int mt = 0; mt < 4; mt++) {
#pragma unroll
    for (int rg = 0; rg < 4; rg++) {
      const int row = mt * 16 + q * 4 + rg;
      const int node = n0 + row;
      if (node < NN) {
        const float mu = mr[row][0], rstd = mr[row][1];
#pragma unroll
        for (int nt = 0; nt < 2; nt++) {
          const float o = (acc[mt][nt][rg] - mu) * rstd * gv[nt] + bv[nt];
          hagg[(size_t)node * 128 + (wv * 2 + nt) * 16 + l15] = f2b(fmaxf(o, 0.f));
        }
      }
    }
  }
}

// ---------------- edge head: T14 pipelined dst-grouped MFMA MLP -------------
// Verified-best structure (559.1us total, k_edge 147.5us). Both random
// gathers prefetched one tile ahead into registers, committed to LDS at loop
// top; raw lgkmcnt barriers keep them in flight across GEMM1/2/3.
// NOTE (rounds 5-10): GEMM2 restructures regress (2x); bank-conflict counter
// is dominated by inherent b128 wide-op serialization, not fixable layout
// pathology (3 layout changes left it at ~13.8M). Kernel is latency-bound
// (all pipes 20-27%); structure is at its measured local optimum.
// LDS: Ue 4096 | Hs/E1 19456 (aliased) | Ds 19456 | E2 8704 = 51712 B.
__global__ __launch_bounds__(256) void k_edge_mfma(
    const unsigned short* __restrict__ hb, const int* __restrict__ csr,
    const int* __restrict__ eidA, const int* __restrict__ dstA,
    const unsigned short* __restrict__ eab, const unsigned short* __restrict__ W1p,
    const unsigned short* __restrict__ wc, void* __restrict__ out,
    const int* __restrict__ flags) {
  __shared__ __align__(16) unsigned char sm[51712];
  unsigned char* const Ue = sm;            // [64][64B]    0..4096
  unsigned char* const Hs = sm + 4096;     // [64][304B]   4096..23552
  unsigned char* const E1 = sm + 4096;     // aliases Hs (barrier-separated)
  unsigned char* const Ds = sm + 23552;    // [64][304B]   23552..43008
  unsigned char* const E2 = sm + 43008;    // [64][136B]   43008..51712
  const int tid = threadIdx.x;
  const int wv = tid >> 6;
  const int L = tid & 63;
  const int l15 = L & 15;
  const int q = L >> 4;
  const int f32 = flags[0];
  const int r4 = tid >> 2, seg = tid & 3;

  // zero the K-padding region of Ue (bytes 16..63 of each 64B row), once.
  for (int i = tid; i < 64 * 12; i += 256)
    *(int*)(Ue + (i / 12) * 64 + 16 + (i % 12) * 4) = 0;

  bf16x8 w1f[2][9];
  float b1v[2];
#pragma unroll
  for (int nt = 0; nt < 2; nt++) {
    const int jj = (wv * 2 + nt) * 16 + l15;
#pragma unroll
    for (int cc = 0; cc < 9; cc++)
      w1f[nt][cc] = *(const bf16x8*)(W1p + jj * 288 + cc * 32 + q * 8);
    b1v[nt] = b2f(wc[O_B1 + jj]);
  }
  bf16x8 w2f[4];
  const int jj2 = wv * 16 + l15;
#pragma unroll
  for (int kc = 0; kc < 4; kc++)
    w2f[kc] = *(const bf16x8*)(wc + O_W2 + jj2 * 128 + kc * 32 + q * 8);
  const float b2v = b2f(wc[O_B2 + jj2]);
  const float b3f = b2f(wc[O_B3]);

  const int NT = NE / 64;

  // -------- prologue: prefetch first tile into registers --------
  int4 hsr0, hsr1, hsr2, hsr3;     // src row fragment
  int4 dsr0, dsr1, dsr2, dsr3;     // dst row fragment
  int4 uer; uer.x = uer.y = uer.z = uer.w = 0;
  {
    const int p0 = blockIdx.x * 64;
    const int s0 = csr[p0 + r4];
    const int d0 = dstA[p0 + r4];
    const unsigned short* gs = hb + (size_t)s0 * 128 + seg * 32;
    const unsigned short* gd = hb + (size_t)d0 * 128 + seg * 32;
    hsr0 = ((const int4*)gs)[0]; hsr1 = ((const int4*)gs)[1];
    hsr2 = ((const int4*)gs)[2]; hsr3 = ((const int4*)gs)[3];
    dsr0 = ((const int4*)gd)[0]; dsr1 = ((const int4*)gd)[1];
    dsr2 = ((const int4*)gd)[2]; dsr3 = ((const int4*)gd)[3];
    if (tid < 64) {
      const int e0 = eidA[p0 + tid];
      uer = *(const int4*)(eab + (size_t)e0 * 8);
    }
  }

  for (int t = blockIdx.x; t < NT; t += gridDim.x) {
    const int pbase = t * 64;
    const int tn = (t + (int)gridDim.x < NT) ? (t + (int)gridDim.x) : t;
    const int pnext = tn * 64;

    // 1. LDS writes from current-tile registers (vmcnt waits auto-inserted)
    if (tid < 64) *(int4*)(Ue + tid * 64) = uer;
    {
      unsigned char* ldst = Hs + r4 * HSTR + seg * 64;
      ((int4*)ldst)[0] = hsr0; ((int4*)ldst)[1] = hsr1;
      ((int4*)ldst)[2] = hsr2; ((int4*)ldst)[3] = hsr3;
      unsigned char* ldd = Ds + r4 * HSTR + seg * 64;
      ((int4*)ldd)[0] = dsr0; ((int4*)ldd)[1] = dsr1;
      ((int4*)ldd)[2] = dsr2; ((int4*)ldd)[3] = dsr3;
    }
    // 2. next-tile index loads (sequential, L2-hot)
    const int sN = csr[pnext + r4];
    const int dN = dstA[pnext + r4];
    int eN = 0;
    if (tid < 64) eN = eidA[pnext + tid];

    LBAR();  // Hs/Ds/Ue visible

    // 3. next-tile row gathers — stay in flight across GEMM1/2/3
    int4 h0, h1, h2, h3, d0, d1, d2, d3;
    {
      const unsigned short* gsn = hb + (size_t)sN * 128 + seg * 32;
      h0 = ((const int4*)gsn)[0]; h1 = ((const int4*)gsn)[1];
      h2 = ((const int4*)gsn)[2]; h3 = ((const int4*)gsn)[3];
      const unsigned short* gdn = hb + (size_t)dN * 128 + seg * 32;
      d0 = ((const int4*)gdn)[0]; d1 = ((const int4*)gdn)[1];
      d2 = ((const int4*)gdn)[2]; d3 = ((const int4*)gdn)[3];
    }
    int4 uen; uen.x = uen.y = uen.z = uen.w = 0;
    if (tid < 64) uen = *(const int4*)(eab + (size_t)eN * 8);

    // 4. GEMM1: e1[64][128]; src (Hs), dst (Ds), ea (Ue) — all from LDS
    f32x4 acc1[4][2];
#pragma unroll
    for (int mt = 0; mt < 4; mt++)
#pragma unroll
      for (int nt = 0; nt < 2; nt++) acc1[mt][nt] = (f32x4)(0.0f);
#pragma unroll
    for (int cc = 0; cc < 4; cc++) {
#pragma unroll
      for (int mt = 0; mt < 4; mt++) {
        const bf16x8 a = *(const bf16x8*)(Hs + (mt * 16 + l15) * HSTR + (cc * 32 + q * 8) * 2);
#pragma unroll
        for (int nt = 0; nt < 2; nt++)
          acc1[mt][nt] = __builtin_amdgcn_mfma_f32_16x16x32_bf16(a, w1f[nt][cc], acc1[mt][nt], 0, 0, 0);
      }
    }
#pragma unroll
    for (int cc = 4; cc < 8; cc++) {
#pragma unroll
      for (int mt = 0; mt < 4; mt++) {
        const bf16x8 a = *(const bf16x8*)(Ds + (mt * 16 + l15) * HSTR + ((cc - 4) * 32 + q * 8) * 2);
#pragma unroll
        for (int nt = 0; nt < 2; nt++)
          acc1[mt][nt] = __builtin_amdgcn_mfma_f32_16x16x32_bf16(a, w1f[nt][cc], acc1[mt][nt], 0, 0, 0);
      }
    }
#pragma unroll
    for (int mt = 0; mt < 4; mt++) {
      const bf16x8 a = *(const bf16x8*)(Ue + (mt * 16 + l15) * 64 + q * 16);
#pragma unroll
      for (int nt = 0; nt < 2; nt++)
        acc1[mt][nt] = __builtin_amdgcn_mfma_f32_16x16x32_bf16(a, w1f[nt][8], acc1[mt][nt], 0, 0, 0);
    }
    LBAR();  // all waves done reading Hs/Ue -> E1 may overwrite Hs

#pragma unroll
    for (int mt = 0; mt < 4; mt++)
#pragma unroll
      for (int nt = 0; nt < 2; nt++)
#pragma unroll
        for (int rg = 0; rg < 4; rg++) {
          const int er = mt * 16 + q * 4 + rg;
          const int jj = (wv * 2 + nt) * 16 + l15;
          *(unsigned short*)(E1 + er * HSTR + jj * 2) =
              f2b(fmaxf(acc1[mt][nt][rg] + b1v[nt], 0.f));
        }
    LBAR();  // E1 visible

    // GEMM2: e2[64][64], wave covers 16 cols, all 64 rows
    f32x4 acc2[4];
#pragma unroll
    for (int mt = 0; mt < 4; mt++) acc2[mt] = (f32x4)(0.0f);
#pragma unroll
    for (int kc = 0; kc < 4; kc++) {
#pragma unroll
      for (int mt = 0; mt < 4; mt++) {
        const bf16x8 a = *(const bf16x8*)(E1 + (mt * 16 + l15) * HSTR + (kc * 32 + q * 8) * 2);
        acc2[mt] = __builtin_amdgcn_mfma_f32_16x16x32_bf16(a, w2f[kc], acc2[mt], 0, 0, 0);
      }
    }
#pragma unroll
    for (int mt = 0; mt < 4; mt++)
#pragma unroll
      for (int rg = 0; rg < 4; rg++) {
        const int er = mt * 16 + q * 4 + rg;
        *(unsigned short*)(E2 + er * 136 + jj2 * 2) =
            f2b(fmaxf(acc2[mt][rg] + b2v, 0.f));
      }
    LBAR();  // E2 visible

    // GEMM3: logit per edge, dot-64 via 4 lane-groups + shuffle; scatter by eid
    const int el = wv * 16 + l15;
    float acc = 0.f;
#pragma unroll
    for (int i4 = 0; i4 < 4; i4++) {
      const bf16x4 v = *(const bf16x4*)(E2 + el * 136 + q * 32 + i4 * 8);
#pragma unroll
      for (int j = 0; j < 4; j++)
        acc += b2f((unsigned short)v[j]) * b2f(wc[O_W3 + q * 16 + i4 * 4 + j]);
    }
    acc += __shfl_xor(acc, 16, 64);
    acc += __shfl_xor(acc, 32, 64);
    if (q == 0) {
      const int e = eidA[pbase + el];
      const float r = acc + b3f;
      if (f32) ((float*)out)[e] = r;
      else     ((unsigned short*)out)[e] = f2b(r);
    }

    // rotate prefetch registers
    hsr0 = h0; hsr1 = h1; hsr2 = h2; hsr3 = h3;
    dsr0 = d0; dsr1 = d1; dsr2 = d2; dsr3 = d3;
    uer = uen;
  }
}

extern "C" void kernel_launch(void* const* d_in, const int* in_sizes, int n_in,
                              void* d_out, int out_size, void* d_ws, size_t ws_size,
                              hipStream_t stream) {
  const void* x  = d_in[0];
  const int*  ei = (const int*)d_in[1];
  const void* ea = d_in[2];

  char* ws = (char*)d_ws;
  int*            flags  = (int*)(ws + WS_FLAGS);
  unsigned short* wc     = (unsigned short*)(ws + WS_WC);
  int*            cnt    = (int*)(ws + WS_CNT);
  int*            rowptr = (int*)(ws + WS_ROWP);
  int*            cursor = (int*)(ws + WS_CUR);
  int*            csr    = (int*)(ws + WS_CSR);
  int*            eidA   = (int*)(ws + WS_EID);
  int*            dstA   = (int*)(ws + WS_DST);
  unsigned short* W1p    = (unsigned short*)(ws + WS_W1P);
  unsigned short* hb0    = (unsigned short*)(ws + WS_HB0);
  unsigned short* hb1    = (unsigned short*)(ws + WS_HB1);
  // bsum lives in the CSR slot: used only between k_scan1 and k_scan3,
  // k_fill overwrites csr afterwards.
  int*            bsum   = (int*)(ws + WS_CSR);

  if (ws_size < WS_NEED) {  // diagnostic: error ≈ 1.35 signals this path
    k_fallback<<<3125, 256, 0, stream>>>((unsigned short*)d_out);
    return;
  }

  k_probe<<<1, 64, 0, stream>>>((const unsigned short*)x, ei, flags);
  k_cvt_w<<<(W_TOTAL + 255) / 256, 256, 0, stream>>>(
      d_in[3], d_in[4], d_in[5], d_in[6], d_in[7], d_in[8], d_in[9],
      d_in[10], d_in[11], d_in[12], d_in[13], d_in[14], d_in[15], wc, flags);
  k_build_w1p<<<144, 256, 0, stream>>>(wc, W1p);

  hipMemsetAsync(cnt, 0, NN * sizeof(int), stream);
  hipMemsetAsync(cursor, 0, NN * sizeof(int), stream);
  k_hist<<<3125, 256, 0, stream>>>(ei, cnt, flags);
  k_scan1<<<SCAN_NB, 256, 0, stream>>>(cnt, rowptr, bsum);
  k_scan2<<<1, 256, 0, stream>>>(bsum);
  k_scan3<<<SCAN_NB, 256, 0, stream>>>(rowptr, bsum);
  k_fill<<<3125, 256, 0, stream>>>(ei, rowptr, cursor, csr, eidA, dstA, flags);

  k_inproj<<<NN * 128 / 256, 256, 0, stream>>>(x, wc, hb0, flags);

  unsigned short* cur = hb0;
  unsigned short* nxt = hb1;
  for (int l = 0; l < 4; l++) {
    k_agg<<<12500, 256, 0, stream>>>(cur, csr, rowptr, nxt);
    k_sage_mfma<<<782, 256, 0, stream>>>(cur, nxt, wc, l);
    unsigned short* tmp = cur; cur = nxt; nxt = tmp;
  }
  // after 4 swaps, final h is in hb0 (= cur); hb1 (= nxt) is free → reuse as eab
  unsigned short* eab = nxt;
  k_cvt_ea<<<3125, 256, 0, stream>>>(ea, eab, flags);
  k_edge_mfma<<<3125, 256, 0, stream>>>(cur, csr, eidA, dstA, eab, W1p, wc, d_out, flags);
}